// Round 16
// baseline (456.254 us; speedup 1.0000x reference)
//
#include <hip/hip_runtime.h>
#include <hip/hip_bf16.h>
#include <math.h>

namespace {

constexpr int Bb   = 2;
constexpr int Ss   = 2048;
constexpr int Dd   = 1024;
constexpr int Hh   = 8;
constexpr int DKk  = 128;
constexpr int KTOP = 512;
constexpr int BH    = Bb * Hh;   // 16
constexpr int MROWS = Bb * Ss;   // 4096
constexpr float SCALE = 0.08838834764831845f;  // 1/sqrt(128)

typedef __attribute__((ext_vector_type(8))) short short8t;  // 8 bf16 = 16 B
typedef __attribute__((ext_vector_type(4))) short short4t;  // 4 bf16 = 8 B
typedef __attribute__((ext_vector_type(4))) float f32x4;

__device__ inline ushort f2bf(float x) {  // f32 -> bf16 RNE
  const unsigned u = __float_as_uint(x);
  return (ushort)((u + 0x7FFFu + ((u >> 16) & 1u)) >> 16);
}
__device__ inline float bf2f(ushort h) {
  return __uint_as_float(((unsigned)h) << 16);
}
struct HL { short h, l; };
__device__ inline HL split1(float x) {
  HL r;
  const ushort hu = f2bf(x);
  r.h = (short)hu;
  r.l = (short)f2bf(x - bf2f(hu));
  return r;
}

__device__ inline unsigned key_of(float v) {
  const unsigned u = __float_as_uint(v);
  return (u & 0x80000000u) ? ~u : (u | 0x80000000u);
}
__device__ inline float key_to_float(unsigned k) {
  const unsigned u = (k & 0x80000000u) ? (k & 0x7FFFFFFFu) : ~k;
  return __uint_as_float(u);
}

// async global->LDS, 16 B per lane; LDS dest = uniform base + lane*16
__device__ inline void gload16(const void* g, void* l) {
  __builtin_amdgcn_global_load_lds(
      (const __attribute__((address_space(1))) unsigned int*)g,
      (__attribute__((address_space(3))) unsigned int*)l, 16, 0, 0);
}

// ---------------------------------------------------------------------------
// Pre-split raw inputs ONCE: z=0 query->hi/lo, z=1 key->hi/lo, z=2 value->bf16
// ---------------------------------------------------------------------------
__global__ __launch_bounds__(256) void split_inputs(
    const float* __restrict__ query, const float* __restrict__ keyi,
    const float* __restrict__ value,
    ushort* __restrict__ qsh, ushort* __restrict__ qsl,
    ushort* __restrict__ ksh, ushort* __restrict__ ksl,
    ushort* __restrict__ vsb)
{
  const int z = blockIdx.y;
  const size_t i = ((size_t)blockIdx.x * 256 + threadIdx.x) * 8;
  const float* src = (z == 0) ? query : (z == 1) ? keyi : value;
  const float4 v0 = *(const float4*)(src + i);
  const float4 v1 = *(const float4*)(src + i + 4);
  if (z < 2) {
    ushort* oh = (z == 0) ? qsh : ksh;
    ushort* ol = (z == 0) ? qsl : ksl;
    short8t h, lo;
    HL r;
    r = split1(v0.x); h[0] = r.h; lo[0] = r.l;
    r = split1(v0.y); h[1] = r.h; lo[1] = r.l;
    r = split1(v0.z); h[2] = r.h; lo[2] = r.l;
    r = split1(v0.w); h[3] = r.h; lo[3] = r.l;
    r = split1(v1.x); h[4] = r.h; lo[4] = r.l;
    r = split1(v1.y); h[5] = r.h; lo[5] = r.l;
    r = split1(v1.z); h[6] = r.h; lo[6] = r.l;
    r = split1(v1.w); h[7] = r.h; lo[7] = r.l;
    *(short8t*)(oh + i) = h;
    *(short8t*)(ol + i) = lo;
  } else {
    short8t h;
    h[0] = (short)f2bf(v0.x); h[1] = (short)f2bf(v0.y);
    h[2] = (short)f2bf(v0.z); h[3] = (short)f2bf(v0.w);
    h[4] = (short)f2bf(v1.x); h[5] = (short)f2bf(v1.y);
    h[6] = (short)f2bf(v1.z); h[7] = (short)f2bf(v1.w);
    *(short8t*)(vsb + i) = h;
  }
}

// ---------------------------------------------------------------------------
// Weight prep, fused: z=0 Wq->hi/lo, z=1 Wk->hi/lo, z=2 Wv->bf16, z=3 Wo->bf16
// (all transposed)
// ---------------------------------------------------------------------------
__global__ __launch_bounds__(256) void transpose_prep(
    const float* __restrict__ Wq, const float* __restrict__ Wk,
    const float* __restrict__ Wv, const float* __restrict__ Wo,
    ushort* __restrict__ WqTh, ushort* __restrict__ WqTl,
    ushort* __restrict__ WkTh, ushort* __restrict__ WkTl,
    ushort* __restrict__ WvT,  ushort* __restrict__ WoT)
{
  __shared__ float tile[32][33];
  const int z = blockIdx.z;
  const float* W = (z == 0) ? Wq : (z == 1) ? Wk : (z == 2) ? Wv : Wo;
  const int t  = threadIdx.x;
  const int c0 = blockIdx.x * 32, r0 = blockIdx.y * 32;
  const int lr = t >> 3, lc4 = (t & 7) * 4;
  const float4 v = *(const float4*)(W + (size_t)(r0 + lr) * Dd + c0 + lc4);
  tile[lr][lc4 + 0] = v.x; tile[lr][lc4 + 1] = v.y;
  tile[lr][lc4 + 2] = v.z; tile[lr][lc4 + 3] = v.w;
  __syncthreads();
  const int oc = t >> 3, or4 = (t & 7) * 4;
  const size_t o = (size_t)(c0 + oc) * Dd + r0 + or4;
  if (z < 2) {
    ushort* Th = (z == 0) ? WqTh : WkTh;
    ushort* Tl = (z == 0) ? WqTl : WkTl;
    short4t oh, ol;
    HL r;
    r = split1(tile[or4 + 0][oc]); oh[0] = r.h; ol[0] = r.l;
    r = split1(tile[or4 + 1][oc]); oh[1] = r.h; ol[1] = r.l;
    r = split1(tile[or4 + 2][oc]); oh[2] = r.h; ol[2] = r.l;
    r = split1(tile[or4 + 3][oc]); oh[3] = r.h; ol[3] = r.l;
    *(short4t*)(Th + o) = oh;
    *(short4t*)(Tl + o) = ol;
  } else {
    ushort* Wt = (z == 2) ? WvT : WoT;
    short4t ov;
    ov[0] = (short)f2bf(tile[or4 + 0][oc]);
    ov[1] = (short)f2bf(tile[or4 + 1][oc]);
    ov[2] = (short)f2bf(tile[or4 + 2][oc]);
    ov[3] = (short)f2bf(tile[or4 + 3][oc]);
    *(short4t*)(Wt + o) = ov;
  }
}

// ---------------------------------------------------------------------------
// Batched Q/K/V projection: 128x128 / BK=32 / 4 waves, async global_load_lds
// staging with source-side swizzle. z: 0=Q, 1=K (3-term); 2=V (1-term -> Vt).
// ---------------------------------------------------------------------------
__global__ __launch_bounds__(256) void mfma_proj(
    const ushort* __restrict__ qsh, const ushort* __restrict__ qsl,
    const ushort* __restrict__ ksh, const ushort* __restrict__ ksl,
    const ushort* __restrict__ vsb,
    const ushort* __restrict__ WqTh, const ushort* __restrict__ WqTl,
    const ushort* __restrict__ WkTh, const ushort* __restrict__ WkTl,
    const ushort* __restrict__ WvT,
    const float* __restrict__ bq, const float* __restrict__ bk,
    const float* __restrict__ bv,
    ushort* __restrict__ Qh, ushort* __restrict__ Ql,
    ushort* __restrict__ Kh, ushort* __restrict__ Kl,
    ushort* __restrict__ Vt)
{
  __shared__ ushort Ah[128 * 32];
  __shared__ ushort Al[128 * 32];
  __shared__ ushort Bh[128 * 32];
  __shared__ ushort Bl[128 * 32];
  const int t  = threadIdx.x;
  const int z  = blockIdx.z;
  const int m0 = blockIdx.x * 128;
  const int n0 = blockIdx.y * 128;
  const int l  = t & 63, wv = t >> 6;
  const int wr = wv >> 1, wc = wv & 1;
  const int lrow = l & 15, lhi = l >> 4;

  const ushort* Ah_g = (z == 0) ? qsh : (z == 1) ? ksh : vsb;
  const ushort* Al_g = (z == 0) ? qsl : (z == 1) ? ksl : nullptr;
  const ushort* Bth  = (z == 0) ? WqTh : (z == 1) ? WkTh : WvT;
  const ushort* Btl  = (z == 0) ? WqTl : (z == 1) ? WkTl : nullptr;
  const float*  bias = (z == 0) ? bq   : (z == 1) ? bk   : bv;
  const bool    splitTerms = (z < 2);

  f32x4 acc[4][4] = {};

  for (int kt = 0; kt < Dd; kt += 32) {
#pragma unroll
    for (int p = 0; p < 2; ++p) {
      const int baseRow = p * 64 + wv * 16;
      const int row  = baseRow + (l >> 2);
      const int gl   = (l & 3) ^ (row & 3);
      const size_t ao = (size_t)(m0 + row) * Dd + kt + gl * 8;
      const size_t bo = (size_t)(n0 + row) * Dd + kt + gl * 8;
      gload16(Ah_g + ao, &Ah[baseRow * 32]);
      gload16(Bth + bo, &Bh[baseRow * 32]);
      if (splitTerms) {
        gload16(Al_g + ao, &Al[baseRow * 32]);
        gload16(Btl + bo, &Bl[baseRow * 32]);
      }
    }
    __syncthreads();

    short8t ah[4], al[4], bh[4], bl[4];
#pragma unroll
    for (int i = 0; i < 4; ++i) {
      const int row = wr * 64 + i * 16 + lrow;
      const int idx = row * 32 + ((lhi ^ (row & 3)) << 3);
      ah[i] = *(const short8t*)&Ah[idx];
      if (splitTerms) al[i] = *(const short8t*)&Al[idx];
    }
#pragma unroll
    for (int j = 0; j < 4; ++j) {
      const int row = wc * 64 + j * 16 + lrow;
      const int idx = row * 32 + ((lhi ^ (row & 3)) << 3);
      bh[j] = *(const short8t*)&Bh[idx];
      if (splitTerms) bl[j] = *(const short8t*)&Bl[idx];
    }
#pragma unroll
    for (int i = 0; i < 4; ++i)
#pragma unroll
      for (int j = 0; j < 4; ++j) {
        acc[i][j] = __builtin_amdgcn_mfma_f32_16x16x32_bf16(ah[i], bh[j], acc[i][j], 0, 0, 0);
        if (splitTerms) {
          acc[i][j] = __builtin_amdgcn_mfma_f32_16x16x32_bf16(ah[i], bl[j], acc[i][j], 0, 0, 0);
          acc[i][j] = __builtin_amdgcn_mfma_f32_16x16x32_bf16(al[i], bh[j], acc[i][j], 0, 0, 0);
        }
      }
    __syncthreads();
  }

#pragma unroll
  for (int i = 0; i < 4; ++i) {
#pragma unroll
    for (int j = 0; j < 4; ++j) {
      const int nn = n0 + wc * 64 + j * 16 + lrow;
#pragma unroll
      for (int r = 0; r < 4; ++r) {
        const int mm = m0 + wr * 64 + i * 16 + lhi * 4 + r;
        const float v = acc[i][j][r] + bias[nn];
        const int bb = mm >> 11, s = mm & (Ss - 1);
        const int hh = nn >> 7,  dk = nn & (DKk - 1);
        if (z < 2) {
          const size_t o = (((size_t)(bb * Hh + hh)) * Ss + s) * DKk + dk;
          const HL rr = split1(v);
          if (z == 0) { Qh[o] = (ushort)rr.h; Ql[o] = (ushort)rr.l; }
          else        { Kh[o] = (ushort)rr.h; Kl[o] = (ushort)rr.l; }
        } else {
          Vt[((size_t)((bb * Hh + hh) * DKk + dk)) * Ss + s] = f2bf(v);
        }
      }
    }
  }
}

// ---------------------------------------------------------------------------
// Scores from pre-split Q,K, async-staged; epilogue writes u32 keys (SCALE in)
// ---------------------------------------------------------------------------
__global__ __launch_bounds__(256) void mfma_scores(
    const ushort* __restrict__ Qh, const ushort* __restrict__ Ql,
    const ushort* __restrict__ Kh, const ushort* __restrict__ Kl,
    unsigned* __restrict__ wtsOut)
{
  __shared__ ushort Ah[128 * 32];
  __shared__ ushort Al[128 * 32];
  __shared__ ushort Bh[128 * 32];
  __shared__ ushort Bl[128 * 32];
  const int t  = threadIdx.x;
  const int z  = blockIdx.z;
  const int n0 = blockIdx.x * 128;   // j
  const int m0 = blockIdx.y * 128;   // q
  const int l  = t & 63, wv = t >> 6;
  const int wr = wv >> 1, wc = wv & 1;
  const int lrow = l & 15, lhi = l >> 4;
  const size_t boff = (size_t)z * Ss * DKk;

  f32x4 acc[4][4] = {};

  for (int kt = 0; kt < DKk; kt += 32) {
#pragma unroll
    for (int p = 0; p < 2; ++p) {
      const int baseRow = p * 64 + wv * 16;
      const int row  = baseRow + (l >> 2);
      const int gl   = (l & 3) ^ (row & 3);
      const size_t ao = boff + (size_t)(m0 + row) * DKk + kt + gl * 8;
      const size_t bo = boff + (size_t)(n0 + row) * DKk + kt + gl * 8;
      gload16(Qh + ao, &Ah[baseRow * 32]);
      gload16(Ql + ao, &Al[baseRow * 32]);
      gload16(Kh + bo, &Bh[baseRow * 32]);
      gload16(Kl + bo, &Bl[baseRow * 32]);
    }
    __syncthreads();

    short8t ah[4], al[4], bh[4], bl[4];
#pragma unroll
    for (int i = 0; i < 4; ++i) {
      const int row = wr * 64 + i * 16 + lrow;
      const int idx = row * 32 + ((lhi ^ (row & 3)) << 3);
      ah[i] = *(const short8t*)&Ah[idx];
      al[i] = *(const short8t*)&Al[idx];
    }
#pragma unroll
    for (int j = 0; j < 4; ++j) {
      const int row = wc * 64 + j * 16 + lrow;
      const int idx = row * 32 + ((lhi ^ (row & 3)) << 3);
      bh[j] = *(const short8t*)&Bh[idx];
      bl[j] = *(const short8t*)&Bl[idx];
    }
#pragma unroll
    for (int i = 0; i < 4; ++i)
#pragma unroll
      for (int j = 0; j < 4; ++j) {
        acc[i][j] = __builtin_amdgcn_mfma_f32_16x16x32_bf16(ah[i], bh[j], acc[i][j], 0, 0, 0);
        acc[i][j] = __builtin_amdgcn_mfma_f32_16x16x32_bf16(ah[i], bl[j], acc[i][j], 0, 0, 0);
        acc[i][j] = __builtin_amdgcn_mfma_f32_16x16x32_bf16(al[i], bh[j], acc[i][j], 0, 0, 0);
      }
    __syncthreads();
  }

#pragma unroll
  for (int i = 0; i < 4; ++i)
#pragma unroll
    for (int j = 0; j < 4; ++j) {
      const int nn = n0 + wc * 64 + j * 16 + lrow;
#pragma unroll
      for (int r = 0; r < 4; ++r) {
        const int mm = m0 + wr * 64 + i * 16 + lhi * 4 + r;
        wtsOut[(size_t)z * Ss * Ss + (size_t)mm * Ss + nn] =
            key_of(acc[i][j][r] * SCALE);
      }
    }
}

// ---------------------------------------------------------------------------
// Fused top-512+softmax+PV. One block = 16 rows of one bh (4 waves).
// Phase 1: wave-per-row v6 selector, 4 sequential rows/wave, writes f32
//          weights to d_out (stays in this CU's L1 / XCD L2).
// Phase 2: cooperative 16x128 PV; A-frags read back from the L1/L2-hot
//          weights (f2bf inline), B-frags from L2-resident Vt; K split 4-way;
//          LDS tree reduction; wave 0 stores bf16 attn.
// ---------------------------------------------------------------------------
__global__ __launch_bounds__(256) void topk_pv(
    float* __restrict__ wts, const ushort* __restrict__ VtAll,
    ushort* __restrict__ attnb)
{
  __shared__ unsigned histAll[4][1088];   // 17.4 KB (phase 1)
  __shared__ float    red[2][16][128];    // 16 KB (phase 2 reduce)

  const int t    = threadIdx.x;
  const int lane = t & 63;
  const int wv   = t >> 6;
  const int bh   = blockIdx.x >> 7;
  const int q0   = (blockIdx.x & 127) * 16;
  unsigned* h = histAll[wv];

  // ================= phase 1: top-k + softmax, 4 rows per wave ============
  for (int rr = 0; rr < 4; ++rr) {
    const int row = q0 + wv * 4 + rr;
    float* rowp = wts + ((size_t)bh * Ss + row) * Ss;
    unsigned* rowu = (unsigned*)rowp;

    unsigned k[32];
    unsigned lmax = 0u;
#pragma unroll
    for (int i = 0; i < 8; ++i) {
      const uint4 v = *(const uint4*)(rowu + i * 256 + lane * 4);
      k[i * 4 + 0] = v.x; k[i * 4 + 1] = v.y;
      k[i * 4 + 2] = v.z; k[i * 4 + 3] = v.w;
      lmax = max(max(lmax, max(v.x, v.y)), max(v.z, v.w));
    }
#pragma unroll
    for (int off = 32; off > 0; off >>= 1) lmax = max(lmax, __shfl_xor(lmax, off));
    const float m = key_to_float(lmax);

    unsigned needK = KTOP, tieC = 0u, prefix = 0u;

    // pass 1: bits [31:22], 1024 bins
    {
#pragma unroll
      for (int i = 0; i < 17; ++i) h[lane + i * 64] = 0u;
#pragma unroll
      for (int i = 0; i < 32; ++i) {
        const unsigned b = k[i] >> 22;
        atomicAdd(&h[b + (b >> 4)], 1u);
      }
      unsigned b[16], lsum = 0u;
#pragma unroll
      for (int i = 0; i < 16; ++i) { b[i] = h[lane * 17 + i]; lsum += b[i]; }
      unsigned s = lsum;
#pragma unroll
      for (int off = 1; off < 64; off <<= 1) {
        const unsigned v = __shfl_down(s, off);
        if (lane + off < 64) s += v;
      }
      unsigned run = s - lsum;
      unsigned fb = 0u, fn = 0u, ft = 0u;
      bool found = false;
#pragma unroll
      for (int i = 15; i >= 0; --i) {
        const unsigned c = b[i];
        if (!found && c > 0u && run < needK && run + c >= needK) {
          found = true; fb = (unsigned)(lane * 16 + i); fn = needK - run; ft = c;
        }
        run += c;
      }
      const unsigned long long msk = __ballot(found);
      const int src = (int)__ffsll(msk) - 1;
      prefix = __shfl(fb, src) << 22;
      needK  = __shfl(fn, src);
      tieC   = __shfl(ft, src);
    }

    // passes 2,3: 8-bit refinements (bits [21:14], [13:6])
#pragma unroll
    for (int pass = 0; pass < 2; ++pass) {
      const int sh = (pass == 0) ? 14 : 6;
      const int ph = sh + 8;
#pragma unroll
      for (int i = 0; i < 5; ++i) h[lane + i * 64] = 0u;
      const unsigned pcmp = prefix >> ph;
#pragma unroll
      for (int i = 0; i < 32; ++i) {
        if ((k[i] >> ph) == pcmp) {
          const unsigned b = (k[i] >> sh) & 255u;
          atomicAdd(&h[b + (b >> 4)], 1u);
        }
      }
      unsigned b4[4], lsum = 0u;
#pragma unroll
      for (int i = 0; i < 4; ++i) {
        const unsigned x = (unsigned)(lane * 4 + i);
        b4[i] = h[x + (x >> 4)];
        lsum += b4[i];
      }
      unsigned s = lsum;
#pragma unroll
      for (int off = 1; off < 64; off <<= 1) {
        const unsigned v = __shfl_down(s, off);
        if (lane + off < 64) s += v;
      }
      unsigned run = s - lsum;
      unsigned fb = 0u, fn = 0u, ft = 0u;
      bool found = false;
#pragma unroll
      for (int i = 3; i >= 0; --i) {
        const unsigned c = b4[i];
        if (!found && c > 0u && run < needK && run + c >= needK) {
          found = true; fb = (unsigned)(lane * 4 + i); fn = needK - run; ft = c;
        }
        run += c;
      }
      const unsigned long long msk = __ballot(found);
      const int src = (int)__ffsll(msk) - 1;
      prefix |= __shfl(fb, src) << sh;
      needK   = __shfl(fn, src);
      tieC    = __shfl(ft, src);
    }

    // pass 4: bits [5:0]
    unsigned T;
    {
      h[lane] = 0u;
      if (lane < 4) h[64 + lane] = 0u;
      const unsigned pcmp = prefix >> 6;
#pragma unroll
      for (int i = 0; i < 32; ++i) {
        if ((k[i] >> 6) == pcmp) {
          const unsigned b = k[i] & 63u;
          atomicAdd(&h[b + (b >> 4)], 1u);
        }
      }
      const unsigned b0 = h[lane + (lane >> 4)];
      unsigned s = b0;
#pragma unroll
      for (int off = 1; off < 64; off <<= 1) {
        const unsigned v = __shfl_down(s, off);
        if (lane + off < 64) s += v;
      }
      const unsigned run = s - b0;
      const bool found = (b0 > 0u && run < needK && run + b0 >= needK);
      const unsigned long long msk = __ballot(found);
      const int src = (int)__ffsll(msk) - 1;
      T     = prefix | (unsigned)__shfl((unsigned)lane, src);
      needK = __shfl(needK - run, src);
      tieC  = __shfl(b0, src);
    }

    if (tieC != needK) {
      unsigned R = 0u;
#pragma unroll
      for (int i = 0; i < 8; ++i) {
        unsigned myEq = 0u;
#pragma unroll
        for (int c = 0; c < 4; ++c) myEq += (k[i * 4 + c] == T);
        unsigned ps = myEq;
#pragma unroll
        for (int off = 1; off < 64; off <<= 1) {
          const unsigned v = __shfl_up(ps, off);
          if (lane >= off) ps += v;
        }
        unsigned before = R + ps - myEq;
#pragma unroll
        for (int c = 0; c < 4; ++c) {
          if (k[i * 4 + c] == T) {
            if (before >= needK) k[i * 4 + c] = 0u;
            ++before;
          }
        }
        R += __shfl(ps, 63);
      }
    }

    float lz = 0.f;
#pragma unroll
    for (int i = 0; i < 32; ++i) {
      const unsigned kk = k[i];
      const float w = (kk >= T) ? __expf(key_to_float(kk) - m) : 0.f;
      k[i] = __float_as_uint(w);
      lz += w;
    }
#pragma unroll
    for (int off = 32; off > 0; off >>= 1) lz += __shfl_xor(lz, off);
    const float Zi = 1.0f / lz;

#pragma unroll
    for (int i = 0; i < 8; ++i) {
      float4 o;
      o.x = __uint_as_float(k[i * 4 + 0]) * Zi;
      o.y = __uint_as_float(k[i * 4 + 1]) * Zi;
      o.z = __uint_as_float(k[i * 4 + 2]) * Zi;
      o.w = __uint_as_float(k[i * 4 + 3]) * Zi;
      *(float4*)(rowu + i * 256 + lane * 4) = o;
    }
  }

  __syncthreads();  // drains vmcnt: all 16 rows' weights visible (L1/L2)

  // ================= phase 2: PV 16x128, K split across 4 waves ===========
  const float*  wrow0 = wts + ((size_t)bh * Ss + q0) * Ss;
  const ushort* Vt    = VtAll + (size_t)bh * DKk * Ss;
  const int lrow = lane & 15, lhi = lane >> 4;

  f32x4 acc[8] = {};
  const int j0base = wv * 512;
  for (int ks = 0; ks < 16; ++ks) {
    const int j0 = j0base + ks * 32;
    // A-frag: weights rows (M=16), f32 -> bf16 inline (L1/L2-hot)
    const float* ap = wrow0 + (size_t)lrow * Ss + j0 + lhi * 8;
    const float4 a0 = *(const float4*)ap;
    const float4 a1 = *(const float4*)(ap + 4);
    short8t af;
    af[0] = (short)f2bf(a0.x); af[1] = (short)f2bf(a0.y);
    af[2] = (short)f2bf(a0.z); af[3] = (short)f2bf(a0.w);
    af[4] = (short)f2bf(a1.x); af[5] = (short)f2bf(a1.y);
    af[6] = (short)f2bf(a1.z); af[7] = (short)f2bf(a1.w);
#pragma unroll
    for (int jt = 0; jt < 8; ++jt) {
      const short8t bf_ = *(const short8t*)(
          Vt + (size_t)(jt * 16 + lrow) * Ss + j0 + lhi * 8);
      acc[jt] = __builtin_amdgcn_mfma_f32_16x16x32_bf16(af, bf_, acc[jt], 0, 0, 0);
    }
  }

  // tree reduction across 4 waves
  if (wv >= 2) {
#pragma unroll
    for (int jt = 0; jt < 8; ++jt)
#pragma unroll
      for (int r = 0; r < 4; ++r)
        red[wv - 2][lhi * 4 + r][jt * 16 + lrow] = acc[jt][r];
  }
  __syncthreads();
  if (wv < 2) {
#pragma unroll
    for (int jt = 0; jt < 8; ++jt)
#pragma unroll
      for (int r = 0; r < 4; ++r)
        acc[jt][r] += red[wv][lhi * 4 + r][jt * 16 + lrow];
  }
  __syncthreads();
  if (wv == 1) {
#pragma unroll
    for (int jt = 0; jt < 8; ++jt)
#pragma unroll
      for (int r = 0; r < 4; ++r)
        red[0][lhi * 4 + r][jt * 16 + lrow] = acc[jt][r];
  }
  __syncthreads();
  if (wv == 0) {
    const int bb = bh >> 3, hh = bh & 7;
#pragma unroll
    for (int jt = 0; jt < 8; ++jt)
#pragma unroll
      for (int r = 0; r < 4; ++r) {
        const int row = lhi * 4 + r;
        const int dk  = jt * 16 + lrow;
        const float v = acc[jt][r] + red[0][row][dk];
        attnb[((size_t)(bb * Ss + q0 + row)) * Dd + hh * DKk + dk] = f2bf(v);
      }
  }
}

// ---------------------------------------------------------------------------
// o_proj: A = attnb bf16, fully async staging
// ---------------------------------------------------------------------------
__global__ __launch_bounds__(256) void mfma_oproj(
    const ushort* __restrict__ Ab, const ushort* __restrict__ Bt,
    const float* __restrict__ bias, float* __restrict__ Cout)
{
  __shared__ ushort As[128 * 64];
  __shared__ ushort Bs[128 * 64];
  const int t  = threadIdx.x;
  const int m0 = blockIdx.x * 128;
  const int n0 = blockIdx.y * 128;
  const int l  = t & 63, wv = t >> 6;
  const int wr = wv >> 1, wc = wv & 1;
  const int lrow = l & 15, lhi = l >> 4;

  f32x4 acc[4][4] = {};

  for (int kt = 0; kt < Dd; kt += 64) {
#pragma unroll
    for (int p = 0; p < 4; ++p) {
      const int baseRow = p * 32 + wv * 8;
      const int row = baseRow + (l >> 3);
      const int gl  = (l & 7) ^ (row & 7);
      gload16(Ab + (size_t)(m0 + row) * Dd + kt + gl * 8, &As[baseRow * 64]);
      gload16(Bt + (size_t)(n0 + row) * Dd + kt + gl * 8, &Bs[baseRow * 64]);
    }
    __syncthreads();

#pragma unroll
    for (int kk = 0; kk < 2; ++kk) {
      short8t a[4], b[4];
      const int g = kk * 4 + lhi;
#pragma unroll
      for (int i = 0; i < 4; ++i) {
        const int row = wr * 64 + i * 16 + lrow;
        a[i] = *(const short8t*)&As[row * 64 + ((g ^ (row & 7)) << 3)];
      }
#pragma unroll
      for (int j = 0; j < 4; ++j) {
        const int row = wc * 64 + j * 16 + lrow;
        b[j] = *(const short8t*)&Bs[row * 64 + ((g ^ (row & 7)) << 3)];
      }
#pragma unroll
      for (int i = 0; i < 4; ++i)
#pragma unroll
        for (int j = 0; j < 4; ++j)
          acc[i][j] = __builtin_amdgcn_mfma_f32_16x16x32_bf16(a[i], b[j], acc[i][j], 0, 0, 0);
    }
    __syncthreads();
  }

#pragma unroll
  for (int i = 0; i < 4; ++i)
#pragma unroll
    for (int j = 0; j < 4; ++j) {
      const int nn = n0 + wc * 64 + j * 16 + lrow;
#pragma unroll
      for (int r = 0; r < 4; ++r) {
        const int mm = m0 + wr * 64 + i * 16 + lhi * 4 + r;
        Cout[(size_t)mm * Dd + nn] = acc[i][j][r] + bias[nn];
      }
    }
}

}  // namespace

extern "C" void kernel_launch(void* const* d_in, const int* in_sizes, int n_in,
                              void* d_out_v, int out_size, void* d_ws, size_t ws_size,
                              hipStream_t stream)
{
  const float* query = (const float*)d_in[0];
  const float* key   = (const float*)d_in[1];
  const float* value = (const float*)d_in[2];
  const float* Wq = (const float*)d_in[3];  const float* bq = (const float*)d_in[4];
  const float* Wk = (const float*)d_in[5];  const float* bk = (const float*)d_in[6];
  const float* Wv = (const float*)d_in[7];  const float* bv = (const float*)d_in[8];
  const float* Wo = (const float*)d_in[9];  const float* bo = (const float*)d_in[10];

  float* d_out = (float*)d_out_v;
  float* outp  = d_out;                              // [B,S,D] f32
  float* wts   = d_out + (size_t)Bb * Ss * Dd;       // [B,H,S,S] f32

  const size_t PROJ = (size_t)MROWS * Dd;            // 4M elements
  const size_t DD2  = (size_t)Dd * Dd;               // 1M elements

  ushort* ws    = (ushort*)d_ws;
  ushort* Qh    = ws;                                // 8 MB each
  ushort* Ql    = Qh + PROJ;
  ushort* Kh    = Ql + PROJ;
  ushort* Kl    = Kh + PROJ;                         // ends at 32 MB
  ushort* wreg  = Kl + PROJ;
  ushort* WqTh  = wreg;                              // 4 x 2 MB splits
  ushort* WqTl  = wreg + DD2;
  ushort* WkTh  = wreg + 2 * DD2;
  ushort* WkTl  = wreg + 3 * DD2;
  ushort* WvT   = wreg + 4 * DD2;                    // 2 MB
  ushort* WoT   = wreg + 5 * DD2;                    // 2 MB
  ushort* Vt    = wreg + 6 * DD2;                    // bf16 V^T [16][128][2048] 8 MB
  ushort* attnb = Qh;                                // aliases Qh (dead after scores)

  // pre-split raw inputs live in the (not-yet-written) wts region of d_out
  ushort* qsh = (ushort*)wts;
  ushort* qsl = qsh + PROJ;
  ushort* ksh = qsh + 2 * PROJ;
  ushort* ksl = qsh + 3 * PROJ;
  ushort* vsb = qsh + 4 * PROJ;

  const dim3 blk(256);

  // weight prep (fused, one launch)
  transpose_prep<<<dim3(32, 32, 4), blk, 0, stream>>>(
      Wq, Wk, Wv, Wo, WqTh, WqTl, WkTh, WkTl, WvT, WoT);

  // pre-split inputs (once, elementwise)
  split_inputs<<<dim3((int)(PROJ / 2048), 3), blk, 0, stream>>>(
      query, key, value, qsh, qsl, ksh, ksl, vsb);

  // Q/K/V projections, batched, 128x128 tile, async staging
  mfma_proj<<<dim3(MROWS / 128, Dd / 128, 3), blk, 0, stream>>>(
      qsh, qsl, ksh, ksl, vsb, WqTh, WqTl, WkTh, WkTl, WvT,
      bq, bk, bv, Qh, Ql, Kh, Kl, Vt);

  // scores -> u32 keys in wts region (SCALE folded)
  mfma_scores<<<dim3(Ss / 128, Ss / 128, BH), blk, 0, stream>>>(
      Qh, Ql, Kh, Kl, (unsigned*)wts);

  // fused top-512 + softmax + PV (weights stay L1/L2-hot for the PV read)
  topk_pv<<<dim3(BH * Ss / 16), blk, 0, stream>>>(wts, Vt, attnb);

  // output projection (bf16 A, fully async staging)
  mfma_oproj<<<dim3(MROWS / 128, Dd / 128), blk, 0, stream>>>(
      attnb, WoT, bo, outp);
}

// Round 17
// 393.483 us; speedup vs baseline: 1.1595x; 1.1595x over previous
//
#include <hip/hip_runtime.h>
#include <hip/hip_bf16.h>
#include <math.h>

namespace {

constexpr int Bb   = 2;
constexpr int Ss   = 2048;
constexpr int Dd   = 1024;
constexpr int Hh   = 8;
constexpr int DKk  = 128;
constexpr int KTOP = 512;
constexpr int BH    = Bb * Hh;   // 16
constexpr int MROWS = Bb * Ss;   // 4096
constexpr float SCALE = 0.08838834764831845f;  // 1/sqrt(128)

typedef __attribute__((ext_vector_type(8))) short short8t;  // 8 bf16 = 16 B
typedef __attribute__((ext_vector_type(4))) short short4t;  // 4 bf16 = 8 B
typedef __attribute__((ext_vector_type(4))) float f32x4;

__device__ inline ushort f2bf(float x) {  // f32 -> bf16 RNE
  const unsigned u = __float_as_uint(x);
  return (ushort)((u + 0x7FFFu + ((u >> 16) & 1u)) >> 16);
}
__device__ inline float bf2f(ushort h) {
  return __uint_as_float(((unsigned)h) << 16);
}
struct HL { short h, l; };
__device__ inline HL split1(float x) {
  HL r;
  const ushort hu = f2bf(x);
  r.h = (short)hu;
  r.l = (short)f2bf(x - bf2f(hu));
  return r;
}

__device__ inline unsigned key_of(float v) {
  const unsigned u = __float_as_uint(v);
  return (u & 0x80000000u) ? ~u : (u | 0x80000000u);
}
__device__ inline float key_to_float(unsigned k) {
  const unsigned u = (k & 0x80000000u) ? (k & 0x7FFFFFFFu) : ~k;
  return __uint_as_float(u);
}

// async global->LDS, 16 B per lane; LDS dest = uniform base + lane*16
__device__ inline void gload16(const void* g, void* l) {
  __builtin_amdgcn_global_load_lds(
      (const __attribute__((address_space(1))) unsigned int*)g,
      (__attribute__((address_space(3))) unsigned int*)l, 16, 0, 0);
}

// ---------------------------------------------------------------------------
// Pre-split raw inputs ONCE: z=0 query->hi/lo, z=1 key->hi/lo, z=2 value->bf16
// ---------------------------------------------------------------------------
__global__ __launch_bounds__(256) void split_inputs(
    const float* __restrict__ query, const float* __restrict__ keyi,
    const float* __restrict__ value,
    ushort* __restrict__ qsh, ushort* __restrict__ qsl,
    ushort* __restrict__ ksh, ushort* __restrict__ ksl,
    ushort* __restrict__ vsb)
{
  const int z = blockIdx.y;
  const size_t i = ((size_t)blockIdx.x * 256 + threadIdx.x) * 8;
  const float* src = (z == 0) ? query : (z == 1) ? keyi : value;
  const float4 v0 = *(const float4*)(src + i);
  const float4 v1 = *(const float4*)(src + i + 4);
  if (z < 2) {
    ushort* oh = (z == 0) ? qsh : ksh;
    ushort* ol = (z == 0) ? qsl : ksl;
    short8t h, lo;
    HL r;
    r = split1(v0.x); h[0] = r.h; lo[0] = r.l;
    r = split1(v0.y); h[1] = r.h; lo[1] = r.l;
    r = split1(v0.z); h[2] = r.h; lo[2] = r.l;
    r = split1(v0.w); h[3] = r.h; lo[3] = r.l;
    r = split1(v1.x); h[4] = r.h; lo[4] = r.l;
    r = split1(v1.y); h[5] = r.h; lo[5] = r.l;
    r = split1(v1.z); h[6] = r.h; lo[6] = r.l;
    r = split1(v1.w); h[7] = r.h; lo[7] = r.l;
    *(short8t*)(oh + i) = h;
    *(short8t*)(ol + i) = lo;
  } else {
    short8t h;
    h[0] = (short)f2bf(v0.x); h[1] = (short)f2bf(v0.y);
    h[2] = (short)f2bf(v0.z); h[3] = (short)f2bf(v0.w);
    h[4] = (short)f2bf(v1.x); h[5] = (short)f2bf(v1.y);
    h[6] = (short)f2bf(v1.z); h[7] = (short)f2bf(v1.w);
    *(short8t*)(vsb + i) = h;
  }
}

// ---------------------------------------------------------------------------
// Batched Q/K/V projection, v5: 128x128 / BK=32 / 4 waves, async
// global_load_lds staging with source-side swizzle (LDS stays lane-linear).
// z: 0=Q, 1=K (3-term, out hi/lo [bh][s][dk]); 2=V (1-term, out Vt).
// ---------------------------------------------------------------------------
__global__ __launch_bounds__(256) void mfma_proj(
    const ushort* __restrict__ qsh, const ushort* __restrict__ qsl,
    const ushort* __restrict__ ksh, const ushort* __restrict__ ksl,
    const ushort* __restrict__ vsb,
    const ushort* __restrict__ WqTh, const ushort* __restrict__ WqTl,
    const ushort* __restrict__ WkTh, const ushort* __restrict__ WkTl,
    const ushort* __restrict__ WvT,
    const float* __restrict__ bq, const float* __restrict__ bk,
    const float* __restrict__ bv,
    ushort* __restrict__ Qh, ushort* __restrict__ Ql,
    ushort* __restrict__ Kh, ushort* __restrict__ Kl,
    ushort* __restrict__ Vt)
{
  __shared__ ushort Ah[128 * 32];
  __shared__ ushort Al[128 * 32];
  __shared__ ushort Bh[128 * 32];
  __shared__ ushort Bl[128 * 32];
  const int t  = threadIdx.x;
  const int z  = blockIdx.z;
  const int m0 = blockIdx.x * 128;  // m fastest -> per-XCD A-panel locality
  const int n0 = blockIdx.y * 128;
  const int l  = t & 63, wv = t >> 6;
  const int wr = wv >> 1, wc = wv & 1;
  const int lrow = l & 15, lhi = l >> 4;

  const ushort* Ah_g = (z == 0) ? qsh : (z == 1) ? ksh : vsb;
  const ushort* Al_g = (z == 0) ? qsl : (z == 1) ? ksl : nullptr;
  const ushort* Bth  = (z == 0) ? WqTh : (z == 1) ? WkTh : WvT;
  const ushort* Btl  = (z == 0) ? WqTl : (z == 1) ? WkTl : nullptr;
  const float*  bias = (z == 0) ? bq   : (z == 1) ? bk   : bv;
  const bool    splitTerms = (z < 2);

  f32x4 acc[4][4] = {};

  for (int kt = 0; kt < Dd; kt += 32) {
#pragma unroll
    for (int p = 0; p < 2; ++p) {
      const int baseRow = p * 64 + wv * 16;          // wave-uniform
      const int row  = baseRow + (l >> 2);
      const int gl   = (l & 3) ^ (row & 3);          // pre-swizzled source granule
      const size_t ao = (size_t)(m0 + row) * Dd + kt + gl * 8;
      const size_t bo = (size_t)(n0 + row) * Dd + kt + gl * 8;
      gload16(Ah_g + ao, &Ah[baseRow * 32]);
      gload16(Bth + bo, &Bh[baseRow * 32]);
      if (splitTerms) {
        gload16(Al_g + ao, &Al[baseRow * 32]);
        gload16(Btl + bo, &Bl[baseRow * 32]);
      }
    }
    __syncthreads();

    short8t ah[4], al[4], bh[4], bl[4];
#pragma unroll
    for (int i = 0; i < 4; ++i) {
      const int row = wr * 64 + i * 16 + lrow;
      const int idx = row * 32 + ((lhi ^ (row & 3)) << 3);
      ah[i] = *(const short8t*)&Ah[idx];
      if (splitTerms) al[i] = *(const short8t*)&Al[idx];
    }
#pragma unroll
    for (int j = 0; j < 4; ++j) {
      const int row = wc * 64 + j * 16 + lrow;
      const int idx = row * 32 + ((lhi ^ (row & 3)) << 3);
      bh[j] = *(const short8t*)&Bh[idx];
      if (splitTerms) bl[j] = *(const short8t*)&Bl[idx];
    }
#pragma unroll
    for (int i = 0; i < 4; ++i)
#pragma unroll
      for (int j = 0; j < 4; ++j) {
        acc[i][j] = __builtin_amdgcn_mfma_f32_16x16x32_bf16(ah[i], bh[j], acc[i][j], 0, 0, 0);
        if (splitTerms) {
          acc[i][j] = __builtin_amdgcn_mfma_f32_16x16x32_bf16(ah[i], bl[j], acc[i][j], 0, 0, 0);
          acc[i][j] = __builtin_amdgcn_mfma_f32_16x16x32_bf16(al[i], bh[j], acc[i][j], 0, 0, 0);
        }
      }
    __syncthreads();
  }

#pragma unroll
  for (int i = 0; i < 4; ++i) {
#pragma unroll
    for (int j = 0; j < 4; ++j) {
      const int nn = n0 + wc * 64 + j * 16 + lrow;
#pragma unroll
      for (int r = 0; r < 4; ++r) {
        const int mm = m0 + wr * 64 + i * 16 + lhi * 4 + r;
        const float v = acc[i][j][r] + bias[nn];
        const int bb = mm >> 11, s = mm & (Ss - 1);
        const int hh = nn >> 7,  dk = nn & (DKk - 1);
        if (z < 2) {
          const size_t o = (((size_t)(bb * Hh + hh)) * Ss + s) * DKk + dk;
          const HL rr = split1(v);
          if (z == 0) { Qh[o] = (ushort)rr.h; Ql[o] = (ushort)rr.l; }
          else        { Kh[o] = (ushort)rr.h; Kl[o] = (ushort)rr.l; }
        } else {
          Vt[((size_t)((bb * Hh + hh) * DKk + dk)) * Ss + s] = f2bf(v);
        }
      }
    }
  }
}

// ---------------------------------------------------------------------------
// Scores from pre-split Q,K, async-staged; epilogue writes u32 keys (SCALE in)
// ---------------------------------------------------------------------------
__global__ __launch_bounds__(256) void mfma_scores(
    const ushort* __restrict__ Qh, const ushort* __restrict__ Ql,
    const ushort* __restrict__ Kh, const ushort* __restrict__ Kl,
    unsigned* __restrict__ wtsOut)
{
  __shared__ ushort Ah[128 * 32];
  __shared__ ushort Al[128 * 32];
  __shared__ ushort Bh[128 * 32];
  __shared__ ushort Bl[128 * 32];
  const int t  = threadIdx.x;
  const int z  = blockIdx.z;
  const int n0 = blockIdx.x * 128;   // j
  const int m0 = blockIdx.y * 128;   // q
  const int l  = t & 63, wv = t >> 6;
  const int wr = wv >> 1, wc = wv & 1;
  const int lrow = l & 15, lhi = l >> 4;
  const size_t boff = (size_t)z * Ss * DKk;

  f32x4 acc[4][4] = {};

  for (int kt = 0; kt < DKk; kt += 32) {
#pragma unroll
    for (int p = 0; p < 2; ++p) {
      const int baseRow = p * 64 + wv * 16;
      const int row  = baseRow + (l >> 2);
      const int gl   = (l & 3) ^ (row & 3);
      const size_t ao = boff + (size_t)(m0 + row) * DKk + kt + gl * 8;
      const size_t bo = boff + (size_t)(n0 + row) * DKk + kt + gl * 8;
      gload16(Qh + ao, &Ah[baseRow * 32]);
      gload16(Ql + ao, &Al[baseRow * 32]);
      gload16(Kh + bo, &Bh[baseRow * 32]);
      gload16(Kl + bo, &Bl[baseRow * 32]);
    }
    __syncthreads();

    short8t ah[4], al[4], bh[4], bl[4];
#pragma unroll
    for (int i = 0; i < 4; ++i) {
      const int row = wr * 64 + i * 16 + lrow;
      const int idx = row * 32 + ((lhi ^ (row & 3)) << 3);
      ah[i] = *(const short8t*)&Ah[idx];
      al[i] = *(const short8t*)&Al[idx];
    }
#pragma unroll
    for (int j = 0; j < 4; ++j) {
      const int row = wc * 64 + j * 16 + lrow;
      const int idx = row * 32 + ((lhi ^ (row & 3)) << 3);
      bh[j] = *(const short8t*)&Bh[idx];
      bl[j] = *(const short8t*)&Bl[idx];
    }
#pragma unroll
    for (int i = 0; i < 4; ++i)
#pragma unroll
      for (int j = 0; j < 4; ++j) {
        acc[i][j] = __builtin_amdgcn_mfma_f32_16x16x32_bf16(ah[i], bh[j], acc[i][j], 0, 0, 0);
        acc[i][j] = __builtin_amdgcn_mfma_f32_16x16x32_bf16(ah[i], bl[j], acc[i][j], 0, 0, 0);
        acc[i][j] = __builtin_amdgcn_mfma_f32_16x16x32_bf16(al[i], bh[j], acc[i][j], 0, 0, 0);
      }
    __syncthreads();
  }

#pragma unroll
  for (int i = 0; i < 4; ++i)
#pragma unroll
    for (int j = 0; j < 4; ++j) {
      const int nn = n0 + wc * 64 + j * 16 + lrow;
#pragma unroll
      for (int r = 0; r < 4; ++r) {
        const int mm = m0 + wr * 64 + i * 16 + lhi * 4 + r;
        wtsOut[(size_t)z * Ss * Ss + (size_t)mm * Ss + nn] =
            key_of(acc[i][j][r] * SCALE);
      }
    }
}

// ---------------------------------------------------------------------------
// o_proj with inline pv-partial reduce; async B staging
// ---------------------------------------------------------------------------
__global__ __launch_bounds__(256) void mfma_oproj(
    const float* __restrict__ pv0, const float* __restrict__ pv1,
    const ushort* __restrict__ Bt,
    const float* __restrict__ bias, float* __restrict__ Cout)
{
  __shared__ ushort As[128 * 64];
  __shared__ ushort Bs[128 * 64];
  const int t  = threadIdx.x;
  const int m0 = blockIdx.x * 128;
  const int n0 = blockIdx.y * 128;
  const int l  = t & 63, wv = t >> 6;
  const int wr = wv >> 1, wc = wv & 1;
  const int lrow = l & 15, lhi = l >> 4;

  f32x4 acc[4][4] = {};

  for (int kt = 0; kt < Dd; kt += 64) {
#pragma unroll
    for (int p = 0; p < 4; ++p) {
      // B: async with source-side swizzle
      const int baseRow = p * 32 + wv * 8;
      const int brow = baseRow + (l >> 3);
      const int bgl  = (l & 7) ^ (brow & 7);
      gload16(Bt + (size_t)(n0 + brow) * Dd + kt + bgl * 8, &Bs[baseRow * 64]);
      // A: manual (reduce + convert)
      const int li = p * 256 + t, row = li >> 3, g = li & 7;
      const int sw = row * 64 + ((g ^ (row & 7)) << 3);
      const size_t ao = (size_t)(m0 + row) * Dd + kt + g * 8;
      const float4 a0 = *(const float4*)(pv0 + ao);
      const float4 a1 = *(const float4*)(pv0 + ao + 4);
      const float4 c0 = *(const float4*)(pv1 + ao);
      const float4 c1 = *(const float4*)(pv1 + ao + 4);
      short8t sa;
      sa[0] = (short)f2bf(a0.x + c0.x); sa[1] = (short)f2bf(a0.y + c0.y);
      sa[2] = (short)f2bf(a0.z + c0.z); sa[3] = (short)f2bf(a0.w + c0.w);
      sa[4] = (short)f2bf(a1.x + c1.x); sa[5] = (short)f2bf(a1.y + c1.y);
      sa[6] = (short)f2bf(a1.z + c1.z); sa[7] = (short)f2bf(a1.w + c1.w);
      *(short8t*)&As[sw] = sa;
    }
    __syncthreads();

#pragma unroll
    for (int kk = 0; kk < 2; ++kk) {
      short8t a[4], b[4];
      const int g = kk * 4 + lhi;
#pragma unroll
      for (int i = 0; i < 4; ++i) {
        const int row = wr * 64 + i * 16 + lrow;
        a[i] = *(const short8t*)&As[row * 64 + ((g ^ (row & 7)) << 3)];
      }
#pragma unroll
      for (int j = 0; j < 4; ++j) {
        const int row = wc * 64 + j * 16 + lrow;
        b[j] = *(const short8t*)&Bs[row * 64 + ((g ^ (row & 7)) << 3)];
      }
#pragma unroll
      for (int i = 0; i < 4; ++i)
#pragma unroll
        for (int j = 0; j < 4; ++j)
          acc[i][j] = __builtin_amdgcn_mfma_f32_16x16x32_bf16(a[i], b[j], acc[i][j], 0, 0, 0);
    }
    __syncthreads();
  }

#pragma unroll
  for (int i = 0; i < 4; ++i)
#pragma unroll
    for (int j = 0; j < 4; ++j) {
      const int nn = n0 + wc * 64 + j * 16 + lrow;
#pragma unroll
      for (int r = 0; r < 4; ++r) {
        const int mm = m0 + wr * 64 + i * 16 + lhi * 4 + r;
        Cout[(size_t)mm * Dd + nn] = acc[i][j][r] + bias[nn];
      }
    }
}

// ---------------------------------------------------------------------------
// PV with split-K=2: async B staging; A manual (f32->bf16 convert)
// ---------------------------------------------------------------------------
__global__ __launch_bounds__(256) void pv_split(
    const float* __restrict__ Wts, const ushort* __restrict__ VtAll,
    float* __restrict__ pvp)
{
  __shared__ ushort As[128 * 64];
  __shared__ ushort Bs[128 * 64];
  const int t  = threadIdx.x;
  const int ks = blockIdx.x;
  const int m0 = blockIdx.y * 128;
  const int z  = blockIdx.z;
  const int l  = t & 63, wv = t >> 6;
  const int wr = wv >> 1, wc = wv & 1;
  const int lrow = l & 15, lhi = l >> 4;

  const float*  Af = Wts + (size_t)z * Ss * Ss;
  const ushort* Bt = VtAll + (size_t)z * DKk * Ss;

  f32x4 acc[4][4] = {};

  for (int kt = ks * 1024; kt < ks * 1024 + 1024; kt += 64) {
#pragma unroll
    for (int p = 0; p < 4; ++p) {
      // B: async with source-side swizzle (Vt rows = dk, cols = s)
      const int baseRow = p * 32 + wv * 8;
      const int brow = baseRow + (l >> 3);
      const int bgl  = (l & 7) ^ (brow & 7);
      gload16(Bt + (size_t)brow * Ss + kt + bgl * 8, &Bs[baseRow * 64]);
      // A: manual convert
      const int li = p * 256 + t, row = li >> 3, g = li & 7;
      const int sw = row * 64 + ((g ^ (row & 7)) << 3);
      const float* src = Af + (size_t)(m0 + row) * Ss + kt + g * 8;
      const float4 v0 = *(const float4*)src;
      const float4 v1 = *(const float4*)(src + 4);
      short8t sa;
      sa[0] = (short)f2bf(v0.x); sa[1] = (short)f2bf(v0.y);
      sa[2] = (short)f2bf(v0.z); sa[3] = (short)f2bf(v0.w);
      sa[4] = (short)f2bf(v1.x); sa[5] = (short)f2bf(v1.y);
      sa[6] = (short)f2bf(v1.z); sa[7] = (short)f2bf(v1.w);
      *(short8t*)&As[sw] = sa;
    }
    __syncthreads();

#pragma unroll
    for (int kk = 0; kk < 2; ++kk) {
      short8t a[4], b[4];
      const int g = kk * 4 + lhi;
#pragma unroll
      for (int i = 0; i < 4; ++i) {
        const int row = wr * 64 + i * 16 + lrow;
        a[i] = *(const short8t*)&As[row * 64 + ((g ^ (row & 7)) << 3)];
      }
#pragma unroll
      for (int j = 0; j < 4; ++j) {
        const int row = wc * 64 + j * 16 + lrow;
        b[j] = *(const short8t*)&Bs[row * 64 + ((g ^ (row & 7)) << 3)];
      }
#pragma unroll
      for (int i = 0; i < 4; ++i)
#pragma unroll
        for (int j = 0; j < 4; ++j)
          acc[i][j] = __builtin_amdgcn_mfma_f32_16x16x32_bf16(a[i], b[j], acc[i][j], 0, 0, 0);
    }
    __syncthreads();
  }

  const int bb = z >> 3, hh = z & 7;
  float* outp = pvp + (size_t)ks * MROWS * Dd;
#pragma unroll
  for (int i = 0; i < 4; ++i)
#pragma unroll
    for (int j = 0; j < 4; ++j) {
      const int nn = wc * 64 + j * 16 + lrow;
#pragma unroll
      for (int r = 0; r < 4; ++r) {
        const int mm = m0 + wr * 64 + i * 16 + lhi * 4 + r;
        outp[((size_t)(bb * Ss + mm)) * Dd + hh * DKk + nn] = acc[i][j][r];
      }
    }
}

// ---------------------------------------------------------------------------
// W[1024][1024] f32 -> Wt bf16 (transposed)
// ---------------------------------------------------------------------------
__global__ __launch_bounds__(256) void transpose_bf16(
    const float* __restrict__ W, ushort* __restrict__ Wt)
{
  __shared__ float tile[32][33];
  const int t  = threadIdx.x;
  const int c0 = blockIdx.x * 32, r0 = blockIdx.y * 32;
  const int lr = t >> 3, lc4 = (t & 7) * 4;
  const float4 v = *(const float4*)(W + (size_t)(r0 + lr) * Dd + c0 + lc4);
  tile[lr][lc4 + 0] = v.x; tile[lr][lc4 + 1] = v.y;
  tile[lr][lc4 + 2] = v.z; tile[lr][lc4 + 3] = v.w;
  __syncthreads();
  const int oc = t >> 3, or4 = (t & 7) * 4;
  short4t o;
  o[0] = (short)f2bf(tile[or4 + 0][oc]);
  o[1] = (short)f2bf(tile[or4 + 1][oc]);
  o[2] = (short)f2bf(tile[or4 + 2][oc]);
  o[3] = (short)f2bf(tile[or4 + 3][oc]);
  *(short4t*)(Wt + (size_t)(c0 + oc) * Dd + r0 + or4) = o;
}

// ---------------------------------------------------------------------------
// W[1024][1024] f32 -> transposed hi/lo bf16 split
// ---------------------------------------------------------------------------
__global__ __launch_bounds__(256) void transpose_split(
    const float* __restrict__ W, ushort* __restrict__ Th, ushort* __restrict__ Tl)
{
  __shared__ float tile[32][33];
  const int t  = threadIdx.x;
  const int c0 = blockIdx.x * 32, r0 = blockIdx.y * 32;
  const int lr = t >> 3, lc4 = (t & 7) * 4;
  const float4 v = *(const float4*)(W + (size_t)(r0 + lr) * Dd + c0 + lc4);
  tile[lr][lc4 + 0] = v.x; tile[lr][lc4 + 1] = v.y;
  tile[lr][lc4 + 2] = v.z; tile[lr][lc4 + 3] = v.w;
  __syncthreads();
  const int oc = t >> 3, or4 = (t & 7) * 4;
  short4t oh, ol;
  HL r;
  r = split1(tile[or4 + 0][oc]); oh[0] = r.h; ol[0] = r.l;
  r = split1(tile[or4 + 1][oc]); oh[1] = r.h; ol[1] = r.l;
  r = split1(tile[or4 + 2][oc]); oh[2] = r.h; ol[2] = r.l;
  r = split1(tile[or4 + 3][oc]); oh[3] = r.h; ol[3] = r.l;
  *(short4t*)(Th + (size_t)(c0 + oc) * Dd + r0 + or4) = oh;
  *(short4t*)(Tl + (size_t)(c0 + oc) * Dd + r0 + or4) = ol;
}

// ---------------------------------------------------------------------------
// Per-row exact top-512 + softmax, v6: wave-per-row, zero __syncthreads.
// ---------------------------------------------------------------------------
__global__ __launch_bounds__(256) void topk_softmax(float* __restrict__ wts)
{
  __shared__ unsigned histAll[4][1088];

  const int lane = threadIdx.x & 63;
  const int wv   = threadIdx.x >> 6;
  const int row  = blockIdx.x * 4 + wv;
  float* rowp = wts + (size_t)row * Ss;
  unsigned* rowu = (unsigned*)rowp;
  unsigned* h = histAll[wv];

  unsigned k[32];
  unsigned lmax = 0u;
#pragma unroll
  for (int i = 0; i < 8; ++i) {
    const uint4 v = *(const uint4*)(rowu + i * 256 + lane * 4);
    k[i * 4 + 0] = v.x; k[i * 4 + 1] = v.y;
    k[i * 4 + 2] = v.z; k[i * 4 + 3] = v.w;
    lmax = max(max(lmax, max(v.x, v.y)), max(v.z, v.w));
  }
#pragma unroll
  for (int off = 32; off > 0; off >>= 1) lmax = max(lmax, __shfl_xor(lmax, off));
  const float m = key_to_float(lmax);

  unsigned needK = KTOP, tieC = 0u, prefix = 0u;

  // pass 1: bits [31:22], 1024 bins
  {
#pragma unroll
    for (int i = 0; i < 17; ++i) h[lane + i * 64] = 0u;
#pragma unroll
    for (int i = 0; i < 32; ++i) {
      const unsigned b = k[i] >> 22;
      atomicAdd(&h[b + (b >> 4)], 1u);
    }
    unsigned b[16], lsum = 0u;
#pragma unroll
    for (int i = 0; i < 16; ++i) { b[i] = h[lane * 17 + i]; lsum += b[i]; }
    unsigned s = lsum;
#pragma unroll
    for (int off = 1; off < 64; off <<= 1) {
      const unsigned v = __shfl_down(s, off);
      if (lane + off < 64) s += v;
    }
    unsigned run = s - lsum;
    unsigned fb = 0u, fn = 0u, ft = 0u;
    bool found = false;
#pragma unroll
    for (int i = 15; i >= 0; --i) {
      const unsigned c = b[i];
      if (!found && c > 0u && run < needK && run + c >= needK) {
        found = true; fb = (unsigned)(lane * 16 + i); fn = needK - run; ft = c;
      }
      run += c;
    }
    const unsigned long long msk = __ballot(found);
    const int src = (int)__ffsll(msk) - 1;
    prefix = __shfl(fb, src) << 22;
    needK  = __shfl(fn, src);
    tieC   = __shfl(ft, src);
  }

  // passes 2,3: 8-bit refinements (bits [21:14], [13:6])
#pragma unroll
  for (int pass = 0; pass < 2; ++pass) {
    const int sh = (pass == 0) ? 14 : 6;
    const int ph = sh + 8;
#pragma unroll
    for (int i = 0; i < 5; ++i) h[lane + i * 64] = 0u;
    const unsigned pcmp = prefix >> ph;
#pragma unroll
    for (int i = 0; i < 32; ++i) {
      if ((k[i] >> ph) == pcmp) {
        const unsigned b = (k[i] >> sh) & 255u;
        atomicAdd(&h[b + (b >> 4)], 1u);
      }
    }
    unsigned b4[4], lsum = 0u;
#pragma unroll
    for (int i = 0; i < 4; ++i) {
      const unsigned x = (unsigned)(lane * 4 + i);
      b4[i] = h[x + (x >> 4)];
      lsum += b4[i];
    }
    unsigned s = lsum;
#pragma unroll
    for (int off = 1; off < 64; off <<= 1) {
      const unsigned v = __shfl_down(s, off);
      if (lane + off < 64) s += v;
    }
    unsigned run = s - lsum;
    unsigned fb = 0u, fn = 0u, ft = 0u;
    bool found = false;
#pragma unroll
    for (int i = 3; i >= 0; --i) {
      const unsigned c = b4[i];
      if (!found && c > 0u && run < needK && run + c >= needK) {
        found = true; fb = (unsigned)(lane * 4 + i); fn = needK - run; ft = c;
      }
      run += c;
    }
    const unsigned long long msk = __ballot(found);
    const int src = (int)__ffsll(msk) - 1;
    prefix |= __shfl(fb, src) << sh;
    needK   = __shfl(fn, src);
    tieC    = __shfl(ft, src);
  }

  // pass 4: bits [5:0]
  unsigned T;
  {
    h[lane] = 0u;
    if (lane < 4) h[64 + lane] = 0u;
    const unsigned pcmp = prefix >> 6;
#pragma unroll
    for (int i = 0; i < 32; ++i) {
      if ((k[i] >> 6) == pcmp) {
        const unsigned b = k[i] & 63u;
        atomicAdd(&h[b + (b >> 4)], 1u);
      }
    }
    const unsigned b0 = h[lane + (lane >> 4)];
    unsigned s = b0;
#pragma unroll
    for (int off = 1; off < 64; off <<= 1) {
      const unsigned v = __shfl_down(s, off);
      if (lane + off < 64) s += v;
    }
    const unsigned run = s - b0;
    const bool found = (b0 > 0u && run < needK && run + b0 >= needK);
    const unsigned long long msk = __ballot(found);
    const int src = (int)__ffsll(msk) - 1;
    T     = prefix | (unsigned)__shfl((unsigned)lane, src);
    needK = __shfl(needK - run, src);
    tieC  = __shfl(b0, src);
  }

  if (tieC != needK) {
    unsigned R = 0u;
#pragma unroll
    for (int i = 0; i < 8; ++i) {
      unsigned myEq = 0u;
#pragma unroll
      for (int c = 0; c < 4; ++c) myEq += (k[i * 4 + c] == T);
      unsigned ps = myEq;
#pragma unroll
      for (int off = 1; off < 64; off <<= 1) {
        const unsigned v = __shfl_up(ps, off);
        if (lane >= off) ps += v;
      }
      unsigned before = R + ps - myEq;
#pragma unroll
      for (int c = 0; c < 4; ++c) {
        if (k[i * 4 + c] == T) {
          if (before >= needK) k[i * 4 + c] = 0u;
          ++before;
        }
      }
      R += __shfl(ps, 63);
    }
  }

  float lz = 0.f;
#pragma unroll
  for (int i = 0; i < 32; ++i) {
    const unsigned kk = k[i];
    const float w = (kk >= T) ? __expf(key_to_float(kk) - m) : 0.f;
    k[i] = __float_as_uint(w);
    lz += w;
  }
#pragma unroll
  for (int off = 32; off > 0; off >>= 1) lz += __shfl_xor(lz, off);
  const float Zi = 1.0f / lz;

#pragma unroll
  for (int i = 0; i < 8; ++i) {
    float4 o;
    o.x = __uint_as_float(k[i * 4 + 0]) * Zi;
    o.y = __uint_as_float(k[i * 4 + 1]) * Zi;
    o.z = __uint_as_float(k[i * 4 + 2]) * Zi;
    o.w = __uint_as_float(k[i * 4 + 3]) * Zi;
    *(float4*)(rowu + i * 256 + lane * 4) = o;
  }
}

}  // namespace

extern "C" void kernel_launch(void* const* d_in, const int* in_sizes, int n_in,
                              void* d_out_v, int out_size, void* d_ws, size_t ws_size,
                              hipStream_t stream)
{
  const float* query = (const float*)d_in[0];
  const float* key   = (const float*)d_in[1];
  const float* value = (const float*)d_in[2];
  const float* Wq = (const float*)d_in[3];  const float* bq = (const float*)d_in[4];
  const float* Wk = (const float*)d_in[5];  const float* bk = (const float*)d_in[6];
  const float* Wv = (const float*)d_in[7];  const float* bv = (const float*)d_in[8];
  const float* Wo = (const float*)d_in[9];  const float* bo = (const float*)d_in[10];

  float* d_out = (float*)d_out_v;
  float* outp  = d_out;                              // [B,S,D] f32
  float* wts   = d_out + (size_t)Bb * Ss * Dd;       // [B,H,S,S] f32

  const size_t PROJ = (size_t)MROWS * Dd;            // 4M elements
  const size_t DD2  = (size_t)Dd * Dd;               // 1M elements

  ushort* ws    = (ushort*)d_ws;
  ushort* Qh    = ws;                                // 8 MB each
  ushort* Ql    = Qh + PROJ;
  ushort* Kh    = Ql + PROJ;
  ushort* Kl    = Kh + PROJ;                         // ends at 32 MB
  ushort* wreg  = Kl + PROJ;
  ushort* WqTh  = wreg;                              // 4 x 2 MB splits
  ushort* WqTl  = wreg + DD2;
  ushort* WkTh  = wreg + 2 * DD2;
  ushort* WkTl  = wreg + 3 * DD2;
  ushort* WvT   = wreg + 4 * DD2;                    // 2 MB
  ushort* WoT   = wreg + 5 * DD2;                    // 2 MB
  ushort* Vt    = wreg + 6 * DD2;                    // bf16 V^T [16][128][2048] 8 MB
  float*  pvp   = (float*)Qh;                        // pv partials alias Qh..Kl (32 MB)

  // pre-split raw inputs live in the (not-yet-written) wts region of d_out
  ushort* qsh = (ushort*)wts;
  ushort* qsl = qsh + PROJ;
  ushort* ksh = qsh + 2 * PROJ;
  ushort* ksl = qsh + 3 * PROJ;
  ushort* vsb = qsh + 4 * PROJ;

  const dim3 blk(256);

  // weight prep
  transpose_split<<<dim3(32, 32), blk, 0, stream>>>(Wq, WqTh, WqTl);
  transpose_split<<<dim3(32, 32), blk, 0, stream>>>(Wk, WkTh, WkTl);
  transpose_bf16<<<dim3(32, 32), blk, 0, stream>>>(Wv, WvT);
  transpose_bf16<<<dim3(32, 32), blk, 0, stream>>>(Wo, WoT);

  // pre-split inputs (once, elementwise)
  split_inputs<<<dim3((int)(PROJ / 2048), 3), blk, 0, stream>>>(
      query, key, value, qsh, qsl, ksh, ksl, vsb);

  // Q/K/V projections, batched, 128x128 tile, async staging
  mfma_proj<<<dim3(MROWS / 128, Dd / 128, 3), blk, 0, stream>>>(
      qsh, qsl, ksh, ksl, vsb, WqTh, WqTl, WkTh, WkTl, WvT,
      bq, bk, bv, Qh, Ql, Kh, Kl, Vt);

  // scores -> u32 keys in wts region (SCALE folded)
  mfma_scores<<<dim3(Ss / 128, Ss / 128, BH), blk, 0, stream>>>(
      Qh, Ql, Kh, Kl, (unsigned*)wts);

  // exact top-512 + softmax, in place (wave-per-row)
  topk_softmax<<<dim3(BH * Ss / 4), blk, 0, stream>>>(wts);

  // PV split-K=2 -> f32 partials (aliasing dead Qh..Kl)
  pv_split<<<dim3(2, Ss / 128, BH), blk, 0, stream>>>(wts, Vt, pvp);

  // output projection with inline partial-reduce
  mfma_oproj<<<dim3(MROWS / 128, Dd / 128), blk, 0, stream>>>(
      pvp, pvp + (size_t)MROWS * Dd, WoT, bo, outp);
}

// Round 18
// 367.413 us; speedup vs baseline: 1.2418x; 1.0710x over previous
//
#include <hip/hip_runtime.h>
#include <hip/hip_bf16.h>
#include <math.h>

namespace {

constexpr int Bb   = 2;
constexpr int Ss   = 2048;
constexpr int Dd   = 1024;
constexpr int Hh   = 8;
constexpr int DKk  = 128;
constexpr int KTOP = 512;
constexpr int BH    = Bb * Hh;   // 16
constexpr int MROWS = Bb * Ss;   // 4096
constexpr float SCALE = 0.08838834764831845f;  // 1/sqrt(128)

typedef __attribute__((ext_vector_type(8))) short short8t;  // 8 bf16 = 16 B
typedef __attribute__((ext_vector_type(4))) short short4t;  // 4 bf16 = 8 B
typedef __attribute__((ext_vector_type(4))) float f32x4;

__device__ inline ushort f2bf(float x) {  // f32 -> bf16 RNE
  const unsigned u = __float_as_uint(x);
  return (ushort)((u + 0x7FFFu + ((u >> 16) & 1u)) >> 16);
}
__device__ inline float bf2f(ushort h) {
  return __uint_as_float(((unsigned)h) << 16);
}
struct HL { short h, l; };
__device__ inline HL split1(float x) {
  HL r;
  const ushort hu = f2bf(x);
  r.h = (short)hu;
  r.l = (short)f2bf(x - bf2f(hu));
  return r;
}

__device__ inline unsigned key_of(float v) {
  const unsigned u = __float_as_uint(v);
  return (u & 0x80000000u) ? ~u : (u | 0x80000000u);
}
__device__ inline float key_to_float(unsigned k) {
  const unsigned u = (k & 0x80000000u) ? (k & 0x7FFFFFFFu) : ~k;
  return __uint_as_float(u);
}

// async global->LDS, 16 B per lane; LDS dest = uniform base + lane*16
__device__ inline void gload16(const void* g, void* l) {
  __builtin_amdgcn_global_load_lds(
      (const __attribute__((address_space(1))) unsigned int*)g,
      (__attribute__((address_space(3))) unsigned int*)l, 16, 0, 0);
}

// ---------------------------------------------------------------------------
// Pre-split raw inputs ONCE: z=0 query->hi/lo, z=1 key->hi/lo, z=2 value->bf16
// ---------------------------------------------------------------------------
__global__ __launch_bounds__(256) void split_inputs(
    const float* __restrict__ query, const float* __restrict__ keyi,
    const float* __restrict__ value,
    ushort* __restrict__ qsh, ushort* __restrict__ qsl,
    ushort* __restrict__ ksh, ushort* __restrict__ ksl,
    ushort* __restrict__ vsb)
{
  const int z = blockIdx.y;
  const size_t i = ((size_t)blockIdx.x * 256 + threadIdx.x) * 8;
  const float* src = (z == 0) ? query : (z == 1) ? keyi : value;
  const float4 v0 = *(const float4*)(src + i);
  const float4 v1 = *(const float4*)(src + i + 4);
  if (z < 2) {
    ushort* oh = (z == 0) ? qsh : ksh;
    ushort* ol = (z == 0) ? qsl : ksl;
    short8t h, lo;
    HL r;
    r = split1(v0.x); h[0] = r.h; lo[0] = r.l;
    r = split1(v0.y); h[1] = r.h; lo[1] = r.l;
    r = split1(v0.z); h[2] = r.h; lo[2] = r.l;
    r = split1(v0.w); h[3] = r.h; lo[3] = r.l;
    r = split1(v1.x); h[4] = r.h; lo[4] = r.l;
    r = split1(v1.y); h[5] = r.h; lo[5] = r.l;
    r = split1(v1.z); h[6] = r.h; lo[6] = r.l;
    r = split1(v1.w); h[7] = r.h; lo[7] = r.l;
    *(short8t*)(oh + i) = h;
    *(short8t*)(ol + i) = lo;
  } else {
    short8t h;
    h[0] = (short)f2bf(v0.x); h[1] = (short)f2bf(v0.y);
    h[2] = (short)f2bf(v0.z); h[3] = (short)f2bf(v0.w);
    h[4] = (short)f2bf(v1.x); h[5] = (short)f2bf(v1.y);
    h[6] = (short)f2bf(v1.z); h[7] = (short)f2bf(v1.w);
    *(short8t*)(vsb + i) = h;
  }
}

// ---------------------------------------------------------------------------
// Weight prep, fused: z=0 Wq->hi/lo, z=1 Wk->hi/lo, z=2 Wv->bf16, z=3 Wo->bf16
// (all transposed). Ran correctly in r16.
// ---------------------------------------------------------------------------
__global__ __launch_bounds__(256) void transpose_prep(
    const float* __restrict__ Wq, const float* __restrict__ Wk,
    const float* __restrict__ Wv, const float* __restrict__ Wo,
    ushort* __restrict__ WqTh, ushort* __restrict__ WqTl,
    ushort* __restrict__ WkTh, ushort* __restrict__ WkTl,
    ushort* __restrict__ WvT,  ushort* __restrict__ WoT)
{
  __shared__ float tile[32][33];
  const int z = blockIdx.z;
  const float* W = (z == 0) ? Wq : (z == 1) ? Wk : (z == 2) ? Wv : Wo;
  const int t  = threadIdx.x;
  const int c0 = blockIdx.x * 32, r0 = blockIdx.y * 32;
  const int lr = t >> 3, lc4 = (t & 7) * 4;
  const float4 v = *(const float4*)(W + (size_t)(r0 + lr) * Dd + c0 + lc4);
  tile[lr][lc4 + 0] = v.x; tile[lr][lc4 + 1] = v.y;
  tile[lr][lc4 + 2] = v.z; tile[lr][lc4 + 3] = v.w;
  __syncthreads();
  const int oc = t >> 3, or4 = (t & 7) * 4;
  const size_t o = (size_t)(c0 + oc) * Dd + r0 + or4;
  if (z < 2) {
    ushort* Th = (z == 0) ? WqTh : WkTh;
    ushort* Tl = (z == 0) ? WqTl : WkTl;
    short4t oh, ol;
    HL r;
    r = split1(tile[or4 + 0][oc]); oh[0] = r.h; ol[0] = r.l;
    r = split1(tile[or4 + 1][oc]); oh[1] = r.h; ol[1] = r.l;
    r = split1(tile[or4 + 2][oc]); oh[2] = r.h; ol[2] = r.l;
    r = split1(tile[or4 + 3][oc]); oh[3] = r.h; ol[3] = r.l;
    *(short4t*)(Th + o) = oh;
    *(short4t*)(Tl + o) = ol;
  } else {
    ushort* Wt = (z == 2) ? WvT : WoT;
    short4t ov;
    ov[0] = (short)f2bf(tile[or4 + 0][oc]);
    ov[1] = (short)f2bf(tile[or4 + 1][oc]);
    ov[2] = (short)f2bf(tile[or4 + 2][oc]);
    ov[3] = (short)f2bf(tile[or4 + 3][oc]);
    *(short4t*)(Wt + o) = ov;
  }
}

// ---------------------------------------------------------------------------
// Batched Q/K/V projection: 128x128 / BK=32 / 4 waves, async global_load_lds
// staging with source-side swizzle. z: 0=Q, 1=K (3-term); 2=V (1-term -> Vt).
// ---------------------------------------------------------------------------
__global__ __launch_bounds__(256) void mfma_proj(
    const ushort* __restrict__ qsh, const ushort* __restrict__ qsl,
    const ushort* __restrict__ ksh, const ushort* __restrict__ ksl,
    const ushort* __restrict__ vsb,
    const ushort* __restrict__ WqTh, const ushort* __restrict__ WqTl,
    const ushort* __restrict__ WkTh, const ushort* __restrict__ WkTl,
    const ushort* __restrict__ WvT,
    const float* __restrict__ bq, const float* __restrict__ bk,
    const float* __restrict__ bv,
    ushort* __restrict__ Qh, ushort* __restrict__ Ql,
    ushort* __restrict__ Kh, ushort* __restrict__ Kl,
    ushort* __restrict__ Vt)
{
  __shared__ ushort Ah[128 * 32];
  __shared__ ushort Al[128 * 32];
  __shared__ ushort Bh[128 * 32];
  __shared__ ushort Bl[128 * 32];
  const int t  = threadIdx.x;
  const int z  = blockIdx.z;
  const int m0 = blockIdx.x * 128;
  const int n0 = blockIdx.y * 128;
  const int l  = t & 63, wv = t >> 6;
  const int wr = wv >> 1, wc = wv & 1;
  const int lrow = l & 15, lhi = l >> 4;

  const ushort* Ah_g = (z == 0) ? qsh : (z == 1) ? ksh : vsb;
  const ushort* Al_g = (z == 0) ? qsl : (z == 1) ? ksl : nullptr;
  const ushort* Bth  = (z == 0) ? WqTh : (z == 1) ? WkTh : WvT;
  const ushort* Btl  = (z == 0) ? WqTl : (z == 1) ? WkTl : nullptr;
  const float*  bias = (z == 0) ? bq   : (z == 1) ? bk   : bv;
  const bool    splitTerms = (z < 2);

  f32x4 acc[4][4] = {};

  for (int kt = 0; kt < Dd; kt += 32) {
#pragma unroll
    for (int p = 0; p < 2; ++p) {
      const int baseRow = p * 64 + wv * 16;
      const int row  = baseRow + (l >> 2);
      const int gl   = (l & 3) ^ (row & 3);
      const size_t ao = (size_t)(m0 + row) * Dd + kt + gl * 8;
      const size_t bo = (size_t)(n0 + row) * Dd + kt + gl * 8;
      gload16(Ah_g + ao, &Ah[baseRow * 32]);
      gload16(Bth + bo, &Bh[baseRow * 32]);
      if (splitTerms) {
        gload16(Al_g + ao, &Al[baseRow * 32]);
        gload16(Btl + bo, &Bl[baseRow * 32]);
      }
    }
    __syncthreads();

    short8t ah[4], al[4], bh[4], bl[4];
#pragma unroll
    for (int i = 0; i < 4; ++i) {
      const int row = wr * 64 + i * 16 + lrow;
      const int idx = row * 32 + ((lhi ^ (row & 3)) << 3);
      ah[i] = *(const short8t*)&Ah[idx];
      if (splitTerms) al[i] = *(const short8t*)&Al[idx];
    }
#pragma unroll
    for (int j = 0; j < 4; ++j) {
      const int row = wc * 64 + j * 16 + lrow;
      const int idx = row * 32 + ((lhi ^ (row & 3)) << 3);
      bh[j] = *(const short8t*)&Bh[idx];
      if (splitTerms) bl[j] = *(const short8t*)&Bl[idx];
    }
#pragma unroll
    for (int i = 0; i < 4; ++i)
#pragma unroll
      for (int j = 0; j < 4; ++j) {
        acc[i][j] = __builtin_amdgcn_mfma_f32_16x16x32_bf16(ah[i], bh[j], acc[i][j], 0, 0, 0);
        if (splitTerms) {
          acc[i][j] = __builtin_amdgcn_mfma_f32_16x16x32_bf16(ah[i], bl[j], acc[i][j], 0, 0, 0);
          acc[i][j] = __builtin_amdgcn_mfma_f32_16x16x32_bf16(al[i], bh[j], acc[i][j], 0, 0, 0);
        }
      }
    __syncthreads();
  }

#pragma unroll
  for (int i = 0; i < 4; ++i) {
#pragma unroll
    for (int j = 0; j < 4; ++j) {
      const int nn = n0 + wc * 64 + j * 16 + lrow;
#pragma unroll
      for (int r = 0; r < 4; ++r) {
        const int mm = m0 + wr * 64 + i * 16 + lhi * 4 + r;
        const float v = acc[i][j][r] + bias[nn];
        const int bb = mm >> 11, s = mm & (Ss - 1);
        const int hh = nn >> 7,  dk = nn & (DKk - 1);
        if (z < 2) {
          const size_t o = (((size_t)(bb * Hh + hh)) * Ss + s) * DKk + dk;
          const HL rr = split1(v);
          if (z == 0) { Qh[o] = (ushort)rr.h; Ql[o] = (ushort)rr.l; }
          else        { Kh[o] = (ushort)rr.h; Kl[o] = (ushort)rr.l; }
        } else {
          Vt[((size_t)((bb * Hh + hh) * DKk + dk)) * Ss + s] = f2bf(v);
        }
      }
    }
  }
}

// ---------------------------------------------------------------------------
// Scores from pre-split Q,K, async-staged; epilogue writes u32 keys (SCALE in)
// ---------------------------------------------------------------------------
__global__ __launch_bounds__(256) void mfma_scores(
    const ushort* __restrict__ Qh, const ushort* __restrict__ Ql,
    const ushort* __restrict__ Kh, const ushort* __restrict__ Kl,
    unsigned* __restrict__ wtsOut)
{
  __shared__ ushort Ah[128 * 32];
  __shared__ ushort Al[128 * 32];
  __shared__ ushort Bh[128 * 32];
  __shared__ ushort Bl[128 * 32];
  const int t  = threadIdx.x;
  const int z  = blockIdx.z;
  const int n0 = blockIdx.x * 128;   // j
  const int m0 = blockIdx.y * 128;   // q
  const int l  = t & 63, wv = t >> 6;
  const int wr = wv >> 1, wc = wv & 1;
  const int lrow = l & 15, lhi = l >> 4;
  const size_t boff = (size_t)z * Ss * DKk;

  f32x4 acc[4][4] = {};

  for (int kt = 0; kt < DKk; kt += 32) {
#pragma unroll
    for (int p = 0; p < 2; ++p) {
      const int baseRow = p * 64 + wv * 16;
      const int row  = baseRow + (l >> 2);
      const int gl   = (l & 3) ^ (row & 3);
      const size_t ao = boff + (size_t)(m0 + row) * DKk + kt + gl * 8;
      const size_t bo = boff + (size_t)(n0 + row) * DKk + kt + gl * 8;
      gload16(Qh + ao, &Ah[baseRow * 32]);
      gload16(Ql + ao, &Al[baseRow * 32]);
      gload16(Kh + bo, &Bh[baseRow * 32]);
      gload16(Kl + bo, &Bl[baseRow * 32]);
    }
    __syncthreads();

    short8t ah[4], al[4], bh[4], bl[4];
#pragma unroll
    for (int i = 0; i < 4; ++i) {
      const int row = wr * 64 + i * 16 + lrow;
      const int idx = row * 32 + ((lhi ^ (row & 3)) << 3);
      ah[i] = *(const short8t*)&Ah[idx];
      al[i] = *(const short8t*)&Al[idx];
    }
#pragma unroll
    for (int j = 0; j < 4; ++j) {
      const int row = wc * 64 + j * 16 + lrow;
      const int idx = row * 32 + ((lhi ^ (row & 3)) << 3);
      bh[j] = *(const short8t*)&Bh[idx];
      bl[j] = *(const short8t*)&Bl[idx];
    }
#pragma unroll
    for (int i = 0; i < 4; ++i)
#pragma unroll
      for (int j = 0; j < 4; ++j) {
        acc[i][j] = __builtin_amdgcn_mfma_f32_16x16x32_bf16(ah[i], bh[j], acc[i][j], 0, 0, 0);
        acc[i][j] = __builtin_amdgcn_mfma_f32_16x16x32_bf16(ah[i], bl[j], acc[i][j], 0, 0, 0);
        acc[i][j] = __builtin_amdgcn_mfma_f32_16x16x32_bf16(al[i], bh[j], acc[i][j], 0, 0, 0);
      }
    __syncthreads();
  }

#pragma unroll
  for (int i = 0; i < 4; ++i)
#pragma unroll
    for (int j = 0; j < 4; ++j) {
      const int nn = n0 + wc * 64 + j * 16 + lrow;
#pragma unroll
      for (int r = 0; r < 4; ++r) {
        const int mm = m0 + wr * 64 + i * 16 + lhi * 4 + r;
        wtsOut[(size_t)z * Ss * Ss + (size_t)mm * Ss + nn] =
            key_of(acc[i][j][r] * SCALE);
      }
    }
}

// ---------------------------------------------------------------------------
// o_proj with inline pv-partial reduce; async B staging
// ---------------------------------------------------------------------------
__global__ __launch_bounds__(256) void mfma_oproj(
    const float* __restrict__ pv0, const float* __restrict__ pv1,
    const ushort* __restrict__ Bt,
    const float* __restrict__ bias, float* __restrict__ Cout)
{
  __shared__ ushort As[128 * 64];
  __shared__ ushort Bs[128 * 64];
  const int t  = threadIdx.x;
  const int m0 = blockIdx.x * 128;
  const int n0 = blockIdx.y * 128;
  const int l  = t & 63, wv = t >> 6;
  const int wr = wv >> 1, wc = wv & 1;
  const int lrow = l & 15, lhi = l >> 4;

  f32x4 acc[4][4] = {};

  for (int kt = 0; kt < Dd; kt += 64) {
#pragma unroll
    for (int p = 0; p < 4; ++p) {
      const int baseRow = p * 32 + wv * 8;
      const int brow = baseRow + (l >> 3);
      const int bgl  = (l & 7) ^ (brow & 7);
      gload16(Bt + (size_t)(n0 + brow) * Dd + kt + bgl * 8, &Bs[baseRow * 64]);
      const int li = p * 256 + t, row = li >> 3, g = li & 7;
      const int sw = row * 64 + ((g ^ (row & 7)) << 3);
      const size_t ao = (size_t)(m0 + row) * Dd + kt + g * 8;
      const float4 a0 = *(const float4*)(pv0 + ao);
      const float4 a1 = *(const float4*)(pv0 + ao + 4);
      const float4 c0 = *(const float4*)(pv1 + ao);
      const float4 c1 = *(const float4*)(pv1 + ao + 4);
      short8t sa;
      sa[0] = (short)f2bf(a0.x + c0.x); sa[1] = (short)f2bf(a0.y + c0.y);
      sa[2] = (short)f2bf(a0.z + c0.z); sa[3] = (short)f2bf(a0.w + c0.w);
      sa[4] = (short)f2bf(a1.x + c1.x); sa[5] = (short)f2bf(a1.y + c1.y);
      sa[6] = (short)f2bf(a1.z + c1.z); sa[7] = (short)f2bf(a1.w + c1.w);
      *(short8t*)&As[sw] = sa;
    }
    __syncthreads();

#pragma unroll
    for (int kk = 0; kk < 2; ++kk) {
      short8t a[4], b[4];
      const int g = kk * 4 + lhi;
#pragma unroll
      for (int i = 0; i < 4; ++i) {
        const int row = wr * 64 + i * 16 + lrow;
        a[i] = *(const short8t*)&As[row * 64 + ((g ^ (row & 7)) << 3)];
      }
#pragma unroll
      for (int j = 0; j < 4; ++j) {
        const int row = wc * 64 + j * 16 + lrow;
        b[j] = *(const short8t*)&Bs[row * 64 + ((g ^ (row & 7)) << 3)];
      }
#pragma unroll
      for (int i = 0; i < 4; ++i)
#pragma unroll
        for (int j = 0; j < 4; ++j)
          acc[i][j] = __builtin_amdgcn_mfma_f32_16x16x32_bf16(a[i], b[j], acc[i][j], 0, 0, 0);
    }
    __syncthreads();
  }

#pragma unroll
  for (int i = 0; i < 4; ++i)
#pragma unroll
    for (int j = 0; j < 4; ++j) {
      const int nn = n0 + wc * 64 + j * 16 + lrow;
#pragma unroll
      for (int r = 0; r < 4; ++r) {
        const int mm = m0 + wr * 64 + i * 16 + lhi * 4 + r;
        Cout[(size_t)mm * Dd + nn] = acc[i][j][r] + bias[nn];
      }
    }
}

// ---------------------------------------------------------------------------
// PV with split-K=2: async B staging; A manual (f32->bf16 convert)
// ---------------------------------------------------------------------------
__global__ __launch_bounds__(256) void pv_split(
    const float* __restrict__ Wts, const ushort* __restrict__ VtAll,
    float* __restrict__ pvp)
{
  __shared__ ushort As[128 * 64];
  __shared__ ushort Bs[128 * 64];
  const int t  = threadIdx.x;
  const int ks = blockIdx.x;
  const int m0 = blockIdx.y * 128;
  const int z  = blockIdx.z;
  const int l  = t & 63, wv = t >> 6;
  const int wr = wv >> 1, wc = wv & 1;
  const int lrow = l & 15, lhi = l >> 4;

  const float*  Af = Wts + (size_t)z * Ss * Ss;
  const ushort* Bt = VtAll + (size_t)z * DKk * Ss;

  f32x4 acc[4][4] = {};

  for (int kt = ks * 1024; kt < ks * 1024 + 1024; kt += 64) {
#pragma unroll
    for (int p = 0; p < 4; ++p) {
      const int baseRow = p * 32 + wv * 8;
      const int brow = baseRow + (l >> 3);
      const int bgl  = (l & 7) ^ (brow & 7);
      gload16(Bt + (size_t)brow * Ss + kt + bgl * 8, &Bs[baseRow * 64]);
      const int li = p * 256 + t, row = li >> 3, g = li & 7;
      const int sw = row * 64 + ((g ^ (row & 7)) << 3);
      const float* src = Af + (size_t)(m0 + row) * Ss + kt + g * 8;
      const float4 v0 = *(const float4*)src;
      const float4 v1 = *(const float4*)(src + 4);
      short8t sa;
      sa[0] = (short)f2bf(v0.x); sa[1] = (short)f2bf(v0.y);
      sa[2] = (short)f2bf(v0.z); sa[3] = (short)f2bf(v0.w);
      sa[4] = (short)f2bf(v1.x); sa[5] = (short)f2bf(v1.y);
      sa[6] = (short)f2bf(v1.z); sa[7] = (short)f2bf(v1.w);
      *(short8t*)&As[sw] = sa;
    }
    __syncthreads();

#pragma unroll
    for (int kk = 0; kk < 2; ++kk) {
      short8t a[4], b[4];
      const int g = kk * 4 + lhi;
#pragma unroll
      for (int i = 0; i < 4; ++i) {
        const int row = wr * 64 + i * 16 + lrow;
        a[i] = *(const short8t*)&As[row * 64 + ((g ^ (row & 7)) << 3)];
      }
#pragma unroll
      for (int j = 0; j < 4; ++j) {
        const int row = wc * 64 + j * 16 + lrow;
        b[j] = *(const short8t*)&Bs[row * 64 + ((g ^ (row & 7)) << 3)];
      }
#pragma unroll
      for (int i = 0; i < 4; ++i)
#pragma unroll
        for (int j = 0; j < 4; ++j)
          acc[i][j] = __builtin_amdgcn_mfma_f32_16x16x32_bf16(a[i], b[j], acc[i][j], 0, 0, 0);
    }
    __syncthreads();
  }

  const int bb = z >> 3, hh = z & 7;
  float* outp = pvp + (size_t)ks * MROWS * Dd;
#pragma unroll
  for (int i = 0; i < 4; ++i)
#pragma unroll
    for (int j = 0; j < 4; ++j) {
      const int nn = wc * 64 + j * 16 + lrow;
#pragma unroll
      for (int r = 0; r < 4; ++r) {
        const int mm = m0 + wr * 64 + i * 16 + lhi * 4 + r;
        outp[((size_t)(bb * Ss + mm)) * Dd + hh * DKk + nn] = acc[i][j][r];
      }
    }
}

// ---------------------------------------------------------------------------
// Per-row exact top-512 + softmax, v7: wave-per-row, zero __syncthreads,
// EARLY-EXIT radix — when a pass resolves the boundary exactly
// (tieC == needK), T = bin lower bound selects the identical set and the
// remaining refinement passes are skipped (common case: exit after pass 2).
// ---------------------------------------------------------------------------
__global__ __launch_bounds__(256) void topk_softmax(float* __restrict__ wts)
{
  __shared__ unsigned histAll[4][1088];

  const int lane = threadIdx.x & 63;
  const int wv   = threadIdx.x >> 6;
  const int row  = blockIdx.x * 4 + wv;
  float* rowp = wts + (size_t)row * Ss;
  unsigned* rowu = (unsigned*)rowp;
  unsigned* h = histAll[wv];

  unsigned k[32];
  unsigned lmax = 0u;
#pragma unroll
  for (int i = 0; i < 8; ++i) {
    const uint4 v = *(const uint4*)(rowu + i * 256 + lane * 4);
    k[i * 4 + 0] = v.x; k[i * 4 + 1] = v.y;
    k[i * 4 + 2] = v.z; k[i * 4 + 3] = v.w;
    lmax = max(max(lmax, max(v.x, v.y)), max(v.z, v.w));
  }
#pragma unroll
  for (int off = 32; off > 0; off >>= 1) lmax = max(lmax, __shfl_xor(lmax, off));
  const float m = key_to_float(lmax);

  unsigned needK = KTOP, tieC = 0u, prefix = 0u;
  unsigned T;

  // pass 1: bits [31:22], 1024 bins
  {
#pragma unroll
    for (int i = 0; i < 17; ++i) h[lane + i * 64] = 0u;
#pragma unroll
    for (int i = 0; i < 32; ++i) {
      const unsigned b = k[i] >> 22;
      atomicAdd(&h[b + (b >> 4)], 1u);
    }
    unsigned b[16], lsum = 0u;
#pragma unroll
    for (int i = 0; i < 16; ++i) { b[i] = h[lane * 17 + i]; lsum += b[i]; }
    unsigned s = lsum;
#pragma unroll
    for (int off = 1; off < 64; off <<= 1) {
      const unsigned v = __shfl_down(s, off);
      if (lane + off < 64) s += v;
    }
    unsigned run = s - lsum;
    unsigned fb = 0u, fn = 0u, ft = 0u;
    bool found = false;
#pragma unroll
    for (int i = 15; i >= 0; --i) {
      const unsigned c = b[i];
      if (!found && c > 0u && run < needK && run + c >= needK) {
        found = true; fb = (unsigned)(lane * 16 + i); fn = needK - run; ft = c;
      }
      run += c;
    }
    const unsigned long long msk = __ballot(found);
    const int src = (int)__ffsll(msk) - 1;
    prefix = __shfl(fb, src) << 22;
    needK  = __shfl(fn, src);
    tieC   = __shfl(ft, src);
  }
  T = prefix;  // bin lower bound (valid if tieC == needK)

  // passes 2,3: 8-bit refinements — only if boundary not yet resolved
  if (tieC != needK) {
#pragma unroll
    for (int pass = 0; pass < 2; ++pass) {
      const int sh = (pass == 0) ? 14 : 6;
      const int ph = sh + 8;
#pragma unroll
      for (int i = 0; i < 5; ++i) h[lane + i * 64] = 0u;
      const unsigned pcmp = prefix >> ph;
#pragma unroll
      for (int i = 0; i < 32; ++i) {
        if ((k[i] >> ph) == pcmp) {
          const unsigned b = (k[i] >> sh) & 255u;
          atomicAdd(&h[b + (b >> 4)], 1u);
        }
      }
      unsigned b4[4], lsum = 0u;
#pragma unroll
      for (int i = 0; i < 4; ++i) {
        const unsigned x = (unsigned)(lane * 4 + i);
        b4[i] = h[x + (x >> 4)];
        lsum += b4[i];
      }
      unsigned s = lsum;
#pragma unroll
      for (int off = 1; off < 64; off <<= 1) {
        const unsigned v = __shfl_down(s, off);
        if (lane + off < 64) s += v;
      }
      unsigned run = s - lsum;
      unsigned fb = 0u, fn = 0u, ft = 0u;
      bool found = false;
#pragma unroll
      for (int i = 3; i >= 0; --i) {
        const unsigned c = b4[i];
        if (!found && c > 0u && run < needK && run + c >= needK) {
          found = true; fb = (unsigned)(lane * 4 + i); fn = needK - run; ft = c;
        }
        run += c;
      }
      const unsigned long long msk = __ballot(found);
      const int src = (int)__ffsll(msk) - 1;
      prefix |= __shfl(fb, src) << sh;
      needK   = __shfl(fn, src);
      tieC    = __shfl(ft, src);
      if (tieC == needK) break;   // wave-uniform
    }
    T = prefix;

    // pass 4: bits [5:0] — only if still unresolved
    if (tieC != needK) {
      h[lane] = 0u;
      if (lane < 4) h[64 + lane] = 0u;
      const unsigned pcmp = prefix >> 6;
#pragma unroll
      for (int i = 0; i < 32; ++i) {
        if ((k[i] >> 6) == pcmp) {
          const unsigned b = k[i] & 63u;
          atomicAdd(&h[b + (b >> 4)], 1u);
        }
      }
      const unsigned b0 = h[lane + (lane >> 4)];
      unsigned s = b0;
#pragma unroll
      for (int off = 1; off < 64; off <<= 1) {
        const unsigned v = __shfl_down(s, off);
        if (lane + off < 64) s += v;
      }
      const unsigned run = s - b0;
      const bool found = (b0 > 0u && run < needK && run + b0 >= needK);
      const unsigned long long msk = __ballot(found);
      const int src = (int)__ffsll(msk) - 1;
      T     = prefix | (unsigned)__shfl((unsigned)lane, src);
      needK = __shfl(needK - run, src);
      tieC  = __shfl(b0, src);
    }
  }

  // rare: >needK duplicates of T -> keep lowest indices (index order)
  if (tieC != needK) {
    unsigned R = 0u;
#pragma unroll
    for (int i = 0; i < 8; ++i) {
      unsigned myEq = 0u;
#pragma unroll
      for (int c = 0; c < 4; ++c) myEq += (k[i * 4 + c] == T);
      unsigned ps = myEq;
#pragma unroll
      for (int off = 1; off < 64; off <<= 1) {
        const unsigned v = __shfl_up(ps, off);
        if (lane >= off) ps += v;
      }
      unsigned before = R + ps - myEq;
#pragma unroll
      for (int c = 0; c < 4; ++c) {
        if (k[i * 4 + c] == T) {
          if (before >= needK) k[i * 4 + c] = 0u;
          ++before;
        }
      }
      R += __shfl(ps, 63);
    }
  }

  float lz = 0.f;
#pragma unroll
  for (int i = 0; i < 32; ++i) {
    const unsigned kk = k[i];
    const float w = (kk >= T) ? __expf(key_to_float(kk) - m) : 0.f;
    k[i] = __float_as_uint(w);
    lz += w;
  }
#pragma unroll
  for (int off = 32; off > 0; off >>= 1) lz += __shfl_xor(lz, off);
  const float Zi = 1.0f / lz;

#pragma unroll
  for (int i = 0; i < 8; ++i) {
    float4 o;
    o.x = __uint_as_float(k[i * 4 + 0]) * Zi;
    o.y = __uint_as_float(k[i * 4 + 1]) * Zi;
    o.z = __uint_as_float(k[i * 4 + 2]) * Zi;
    o.w = __uint_as_float(k[i * 4 + 3]) * Zi;
    *(float4*)(rowu + i * 256 + lane * 4) = o;
  }
}

}  // namespace

extern "C" void kernel_launch(void* const* d_in, const int* in_sizes, int n_in,
                              void* d_out_v, int out_size, void* d_ws, size_t ws_size,
                              hipStream_t stream)
{
  const float* query = (const float*)d_in[0];
  const float* key   = (const float*)d_in[1];
  const float* value = (const float*)d_in[2];
  const float* Wq = (const float*)d_in[3];  const float* bq = (const float*)d_in[4];
  const float* Wk = (const float*)d_in[5];  const float* bk = (const float*)d_in[6];
  const float* Wv = (const float*)d_in[7];  const float* bv = (const float*)d_in[8];
  const float* Wo = (const float*)d_in[9];  const float* bo = (const float*)d_in[10];

  float* d_out = (float*)d_out_v;
  float* outp  = d_out;                              // [B,S,D] f32
  float* wts   = d_out + (size_t)Bb * Ss * Dd;       // [B,H,S,S] f32

  const size_t PROJ = (size_t)MROWS * Dd;            // 4M elements
  const size_t DD2  = (size_t)Dd * Dd;               // 1M elements

  ushort* ws    = (ushort*)d_ws;
  ushort* Qh    = ws;                                // 8 MB each
  ushort* Ql    = Qh + PROJ;
  ushort* Kh    = Ql + PROJ;
  ushort* Kl    = Kh + PROJ;                         // ends at 32 MB
  ushort* wreg  = Kl + PROJ;
  ushort* WqTh  = wreg;                              // 4 x 2 MB splits
  ushort* WqTl  = wreg + DD2;
  ushort* WkTh  = wreg + 2 * DD2;
  ushort* WkTl  = wreg + 3 * DD2;
  ushort* WvT   = wreg + 4 * DD2;                    // 2 MB
  ushort* WoT   = wreg + 5 * DD2;                    // 2 MB
  ushort* Vt    = wreg + 6 * DD2;                    // bf16 V^T [16][128][2048] 8 MB
  float*  pvp   = (float*)Qh;                        // pv partials alias Qh..Kl (32 MB)

  // pre-split raw inputs live in the (not-yet-written) wts region of d_out
  ushort* qsh = (ushort*)wts;
  ushort* qsl = qsh + PROJ;
  ushort* ksh = qsh + 2 * PROJ;
  ushort* ksl = qsh + 3 * PROJ;
  ushort* vsb = qsh + 4 * PROJ;

  const dim3 blk(256);

  // weight prep (fused, one launch)
  transpose_prep<<<dim3(32, 32, 4), blk, 0, stream>>>(
      Wq, Wk, Wv, Wo, WqTh, WqTl, WkTh, WkTl, WvT, WoT);

  // pre-split inputs (once, elementwise)
  split_inputs<<<dim3((int)(PROJ / 2048), 3), blk, 0, stream>>>(
      query, key, value, qsh, qsl, ksh, ksl, vsb);

  // Q/K/V projections, batched, 128x128 tile, async staging
  mfma_proj<<<dim3(MROWS / 128, Dd / 128, 3), blk, 0, stream>>>(
      qsh, qsl, ksh, ksl, vsb, WqTh, WqTl, WkTh, WkTl, WvT,
      bq, bk, bv, Qh, Ql, Kh, Kl, Vt);

  // scores -> u32 keys in wts region (SCALE folded)
  mfma_scores<<<dim3(Ss / 128, Ss / 128, BH), blk, 0, stream>>>(
      Qh, Ql, Kh, Kl, (unsigned*)wts);

  // exact top-512 + softmax, in place (wave-per-row, early-exit radix)
  topk_softmax<<<dim3(BH * Ss / 4), blk, 0, stream>>>(wts);

  // PV split-K=2 -> f32 partials (aliasing dead Qh..Kl)
  pv_split<<<dim3(2, Ss / 128, BH), blk, 0, stream>>>(wts, Vt, pvp);

  // output projection with inline partial-reduce
  mfma_oproj<<<dim3(MROWS / 128, Dd / 128), blk, 0, stream>>>(
      pvp, pvp + (size_t)MROWS * Dd, WoT, bo, outp);
}

// Round 19
// 363.341 us; speedup vs baseline: 1.2557x; 1.0112x over previous
//
#include <hip/hip_runtime.h>
#include <hip/hip_bf16.h>
#include <math.h>

namespace {

constexpr int Bb   = 2;
constexpr int Ss   = 2048;
constexpr int Dd   = 1024;
constexpr int Hh   = 8;
constexpr int DKk  = 128;
constexpr int KTOP = 512;
constexpr int BH    = Bb * Hh;   // 16
constexpr int MROWS = Bb * Ss;   // 4096
constexpr float SCALE = 0.08838834764831845f;  // 1/sqrt(128)

typedef __attribute__((ext_vector_type(8))) short short8t;  // 8 bf16 = 16 B
typedef __attribute__((ext_vector_type(4))) short short4t;  // 4 bf16 = 8 B
typedef __attribute__((ext_vector_type(4))) float f32x4;

__device__ inline ushort f2bf(float x) {  // f32 -> bf16 RNE
  const unsigned u = __float_as_uint(x);
  return (ushort)((u + 0x7FFFu + ((u >> 16) & 1u)) >> 16);
}
__device__ inline float bf2f(ushort h) {
  return __uint_as_float(((unsigned)h) << 16);
}
struct HL { short h, l; };
__device__ inline HL split1(float x) {
  HL r;
  const ushort hu = f2bf(x);
  r.h = (short)hu;
  r.l = (short)f2bf(x - bf2f(hu));
  return r;
}

__device__ inline unsigned key_of(float v) {
  const unsigned u = __float_as_uint(v);
  return (u & 0x80000000u) ? ~u : (u | 0x80000000u);
}
__device__ inline float key_to_float(unsigned k) {
  const unsigned u = (k & 0x80000000u) ? (k & 0x7FFFFFFFu) : ~k;
  return __uint_as_float(u);
}

// async global->LDS, 16 B per lane; LDS dest = uniform base + lane*16
__device__ inline void gload16(const void* g, void* l) {
  __builtin_amdgcn_global_load_lds(
      (const __attribute__((address_space(1))) unsigned int*)g,
      (__attribute__((address_space(3))) unsigned int*)l, 16, 0, 0);
}

// ---------------------------------------------------------------------------
// Pre-split raw inputs ONCE: z=0 query->hi/lo, z=1 key->hi/lo, z=2 value->bf16
// ---------------------------------------------------------------------------
__global__ __launch_bounds__(256) void split_inputs(
    const float* __restrict__ query, const float* __restrict__ keyi,
    const float* __restrict__ value,
    ushort* __restrict__ qsh, ushort* __restrict__ qsl,
    ushort* __restrict__ ksh, ushort* __restrict__ ksl,
    ushort* __restrict__ vsb)
{
  const int z = blockIdx.y;
  const size_t i = ((size_t)blockIdx.x * 256 + threadIdx.x) * 8;
  const float* src = (z == 0) ? query : (z == 1) ? keyi : value;
  const float4 v0 = *(const float4*)(src + i);
  const float4 v1 = *(const float4*)(src + i + 4);
  if (z < 2) {
    ushort* oh = (z == 0) ? qsh : ksh;
    ushort* ol = (z == 0) ? qsl : ksl;
    short8t h, lo;
    HL r;
    r = split1(v0.x); h[0] = r.h; lo[0] = r.l;
    r = split1(v0.y); h[1] = r.h; lo[1] = r.l;
    r = split1(v0.z); h[2] = r.h; lo[2] = r.l;
    r = split1(v0.w); h[3] = r.h; lo[3] = r.l;
    r = split1(v1.x); h[4] = r.h; lo[4] = r.l;
    r = split1(v1.y); h[5] = r.h; lo[5] = r.l;
    r = split1(v1.z); h[6] = r.h; lo[6] = r.l;
    r = split1(v1.w); h[7] = r.h; lo[7] = r.l;
    *(short8t*)(oh + i) = h;
    *(short8t*)(ol + i) = lo;
  } else {
    short8t h;
    h[0] = (short)f2bf(v0.x); h[1] = (short)f2bf(v0.y);
    h[2] = (short)f2bf(v0.z); h[3] = (short)f2bf(v0.w);
    h[4] = (short)f2bf(v1.x); h[5] = (short)f2bf(v1.y);
    h[6] = (short)f2bf(v1.z); h[7] = (short)f2bf(v1.w);
    *(short8t*)(vsb + i) = h;
  }
}

// ---------------------------------------------------------------------------
// Weight prep, fused: z=0 Wq->hi/lo, z=1 Wk->hi/lo, z=2 Wv->bf16, z=3 Wo->bf16
// ---------------------------------------------------------------------------
__global__ __launch_bounds__(256) void transpose_prep(
    const float* __restrict__ Wq, const float* __restrict__ Wk,
    const float* __restrict__ Wv, const float* __restrict__ Wo,
    ushort* __restrict__ WqTh, ushort* __restrict__ WqTl,
    ushort* __restrict__ WkTh, ushort* __restrict__ WkTl,
    ushort* __restrict__ WvT,  ushort* __restrict__ WoT)
{
  __shared__ float tile[32][33];
  const int z = blockIdx.z;
  const float* W = (z == 0) ? Wq : (z == 1) ? Wk : (z == 2) ? Wv : Wo;
  const int t  = threadIdx.x;
  const int c0 = blockIdx.x * 32, r0 = blockIdx.y * 32;
  const int lr = t >> 3, lc4 = (t & 7) * 4;
  const float4 v = *(const float4*)(W + (size_t)(r0 + lr) * Dd + c0 + lc4);
  tile[lr][lc4 + 0] = v.x; tile[lr][lc4 + 1] = v.y;
  tile[lr][lc4 + 2] = v.z; tile[lr][lc4 + 3] = v.w;
  __syncthreads();
  const int oc = t >> 3, or4 = (t & 7) * 4;
  const size_t o = (size_t)(c0 + oc) * Dd + r0 + or4;
  if (z < 2) {
    ushort* Th = (z == 0) ? WqTh : WkTh;
    ushort* Tl = (z == 0) ? WqTl : WkTl;
    short4t oh, ol;
    HL r;
    r = split1(tile[or4 + 0][oc]); oh[0] = r.h; ol[0] = r.l;
    r = split1(tile[or4 + 1][oc]); oh[1] = r.h; ol[1] = r.l;
    r = split1(tile[or4 + 2][oc]); oh[2] = r.h; ol[2] = r.l;
    r = split1(tile[or4 + 3][oc]); oh[3] = r.h; ol[3] = r.l;
    *(short4t*)(Th + o) = oh;
    *(short4t*)(Tl + o) = ol;
  } else {
    ushort* Wt = (z == 2) ? WvT : WoT;
    short4t ov;
    ov[0] = (short)f2bf(tile[or4 + 0][oc]);
    ov[1] = (short)f2bf(tile[or4 + 1][oc]);
    ov[2] = (short)f2bf(tile[or4 + 2][oc]);
    ov[3] = (short)f2bf(tile[or4 + 3][oc]);
    *(short4t*)(Wt + o) = ov;
  }
}

// ---------------------------------------------------------------------------
// Batched Q/K/V projection: 128x128 / BK=32 / 4 waves, async global_load_lds
// staging with source-side swizzle. z: 0=Q, 1=K (3-term); 2=V (1-term -> Vt).
// ---------------------------------------------------------------------------
__global__ __launch_bounds__(256) void mfma_proj(
    const ushort* __restrict__ qsh, const ushort* __restrict__ qsl,
    const ushort* __restrict__ ksh, const ushort* __restrict__ ksl,
    const ushort* __restrict__ vsb,
    const ushort* __restrict__ WqTh, const ushort* __restrict__ WqTl,
    const ushort* __restrict__ WkTh, const ushort* __restrict__ WkTl,
    const ushort* __restrict__ WvT,
    const float* __restrict__ bq, const float* __restrict__ bk,
    const float* __restrict__ bv,
    ushort* __restrict__ Qh, ushort* __restrict__ Ql,
    ushort* __restrict__ Kh, ushort* __restrict__ Kl,
    ushort* __restrict__ Vt)
{
  __shared__ ushort Ah[128 * 32];
  __shared__ ushort Al[128 * 32];
  __shared__ ushort Bh[128 * 32];
  __shared__ ushort Bl[128 * 32];
  const int t  = threadIdx.x;
  const int z  = blockIdx.z;
  const int m0 = blockIdx.x * 128;
  const int n0 = blockIdx.y * 128;
  const int l  = t & 63, wv = t >> 6;
  const int wr = wv >> 1, wc = wv & 1;
  const int lrow = l & 15, lhi = l >> 4;

  const ushort* Ah_g = (z == 0) ? qsh : (z == 1) ? ksh : vsb;
  const ushort* Al_g = (z == 0) ? qsl : (z == 1) ? ksl : nullptr;
  const ushort* Bth  = (z == 0) ? WqTh : (z == 1) ? WkTh : WvT;
  const ushort* Btl  = (z == 0) ? WqTl : (z == 1) ? WkTl : nullptr;
  const float*  bias = (z == 0) ? bq   : (z == 1) ? bk   : bv;
  const bool    splitTerms = (z < 2);

  f32x4 acc[4][4] = {};

  for (int kt = 0; kt < Dd; kt += 32) {
#pragma unroll
    for (int p = 0; p < 2; ++p) {
      const int baseRow = p * 64 + wv * 16;
      const int row  = baseRow + (l >> 2);
      const int gl   = (l & 3) ^ (row & 3);
      const size_t ao = (size_t)(m0 + row) * Dd + kt + gl * 8;
      const size_t bo = (size_t)(n0 + row) * Dd + kt + gl * 8;
      gload16(Ah_g + ao, &Ah[baseRow * 32]);
      gload16(Bth + bo, &Bh[baseRow * 32]);
      if (splitTerms) {
        gload16(Al_g + ao, &Al[baseRow * 32]);
        gload16(Btl + bo, &Bl[baseRow * 32]);
      }
    }
    __syncthreads();

    short8t ah[4], al[4], bh[4], bl[4];
#pragma unroll
    for (int i = 0; i < 4; ++i) {
      const int row = wr * 64 + i * 16 + lrow;
      const int idx = row * 32 + ((lhi ^ (row & 3)) << 3);
      ah[i] = *(const short8t*)&Ah[idx];
      if (splitTerms) al[i] = *(const short8t*)&Al[idx];
    }
#pragma unroll
    for (int j = 0; j < 4; ++j) {
      const int row = wc * 64 + j * 16 + lrow;
      const int idx = row * 32 + ((lhi ^ (row & 3)) << 3);
      bh[j] = *(const short8t*)&Bh[idx];
      if (splitTerms) bl[j] = *(const short8t*)&Bl[idx];
    }
#pragma unroll
    for (int i = 0; i < 4; ++i)
#pragma unroll
      for (int j = 0; j < 4; ++j) {
        acc[i][j] = __builtin_amdgcn_mfma_f32_16x16x32_bf16(ah[i], bh[j], acc[i][j], 0, 0, 0);
        if (splitTerms) {
          acc[i][j] = __builtin_amdgcn_mfma_f32_16x16x32_bf16(ah[i], bl[j], acc[i][j], 0, 0, 0);
          acc[i][j] = __builtin_amdgcn_mfma_f32_16x16x32_bf16(al[i], bh[j], acc[i][j], 0, 0, 0);
        }
      }
    __syncthreads();
  }

#pragma unroll
  for (int i = 0; i < 4; ++i) {
#pragma unroll
    for (int j = 0; j < 4; ++j) {
      const int nn = n0 + wc * 64 + j * 16 + lrow;
#pragma unroll
      for (int r = 0; r < 4; ++r) {
        const int mm = m0 + wr * 64 + i * 16 + lhi * 4 + r;
        const float v = acc[i][j][r] + bias[nn];
        const int bb = mm >> 11, s = mm & (Ss - 1);
        const int hh = nn >> 7,  dk = nn & (DKk - 1);
        if (z < 2) {
          const size_t o = (((size_t)(bb * Hh + hh)) * Ss + s) * DKk + dk;
          const HL rr = split1(v);
          if (z == 0) { Qh[o] = (ushort)rr.h; Ql[o] = (ushort)rr.l; }
          else        { Kh[o] = (ushort)rr.h; Kl[o] = (ushort)rr.l; }
        } else {
          Vt[((size_t)((bb * Hh + hh) * DKk + dk)) * Ss + s] = f2bf(v);
        }
      }
    }
  }
}

// ---------------------------------------------------------------------------
// Scores from pre-split Q,K, async-staged; epilogue writes u32 keys (SCALE in)
// ---------------------------------------------------------------------------
__global__ __launch_bounds__(256) void mfma_scores(
    const ushort* __restrict__ Qh, const ushort* __restrict__ Ql,
    const ushort* __restrict__ Kh, const ushort* __restrict__ Kl,
    unsigned* __restrict__ wtsOut)
{
  __shared__ ushort Ah[128 * 32];
  __shared__ ushort Al[128 * 32];
  __shared__ ushort Bh[128 * 32];
  __shared__ ushort Bl[128 * 32];
  const int t  = threadIdx.x;
  const int z  = blockIdx.z;
  const int n0 = blockIdx.x * 128;   // j
  const int m0 = blockIdx.y * 128;   // q
  const int l  = t & 63, wv = t >> 6;
  const int wr = wv >> 1, wc = wv & 1;
  const int lrow = l & 15, lhi = l >> 4;
  const size_t boff = (size_t)z * Ss * DKk;

  f32x4 acc[4][4] = {};

  for (int kt = 0; kt < DKk; kt += 32) {
#pragma unroll
    for (int p = 0; p < 2; ++p) {
      const int baseRow = p * 64 + wv * 16;
      const int row  = baseRow + (l >> 2);
      const int gl   = (l & 3) ^ (row & 3);
      const size_t ao = boff + (size_t)(m0 + row) * DKk + kt + gl * 8;
      const size_t bo = boff + (size_t)(n0 + row) * DKk + kt + gl * 8;
      gload16(Qh + ao, &Ah[baseRow * 32]);
      gload16(Ql + ao, &Al[baseRow * 32]);
      gload16(Kh + bo, &Bh[baseRow * 32]);
      gload16(Kl + bo, &Bl[baseRow * 32]);
    }
    __syncthreads();

    short8t ah[4], al[4], bh[4], bl[4];
#pragma unroll
    for (int i = 0; i < 4; ++i) {
      const int row = wr * 64 + i * 16 + lrow;
      const int idx = row * 32 + ((lhi ^ (row & 3)) << 3);
      ah[i] = *(const short8t*)&Ah[idx];
      al[i] = *(const short8t*)&Al[idx];
    }
#pragma unroll
    for (int j = 0; j < 4; ++j) {
      const int row = wc * 64 + j * 16 + lrow;
      const int idx = row * 32 + ((lhi ^ (row & 3)) << 3);
      bh[j] = *(const short8t*)&Bh[idx];
      bl[j] = *(const short8t*)&Bl[idx];
    }
#pragma unroll
    for (int i = 0; i < 4; ++i)
#pragma unroll
      for (int j = 0; j < 4; ++j) {
        acc[i][j] = __builtin_amdgcn_mfma_f32_16x16x32_bf16(ah[i], bh[j], acc[i][j], 0, 0, 0);
        acc[i][j] = __builtin_amdgcn_mfma_f32_16x16x32_bf16(ah[i], bl[j], acc[i][j], 0, 0, 0);
        acc[i][j] = __builtin_amdgcn_mfma_f32_16x16x32_bf16(al[i], bh[j], acc[i][j], 0, 0, 0);
      }
    __syncthreads();
  }

#pragma unroll
  for (int i = 0; i < 4; ++i)
#pragma unroll
    for (int j = 0; j < 4; ++j) {
      const int nn = n0 + wc * 64 + j * 16 + lrow;
#pragma unroll
      for (int r = 0; r < 4; ++r) {
        const int mm = m0 + wr * 64 + i * 16 + lhi * 4 + r;
        wtsOut[(size_t)z * Ss * Ss + (size_t)mm * Ss + nn] =
            key_of(acc[i][j][r] * SCALE);
      }
    }
}

// ---------------------------------------------------------------------------
// o_proj: A = attnb bf16, fully async staging
// ---------------------------------------------------------------------------
__global__ __launch_bounds__(256) void mfma_oproj(
    const ushort* __restrict__ Ab, const ushort* __restrict__ Bt,
    const float* __restrict__ bias, float* __restrict__ Cout)
{
  __shared__ ushort As[128 * 64];
  __shared__ ushort Bs[128 * 64];
  const int t  = threadIdx.x;
  const int m0 = blockIdx.x * 128;
  const int n0 = blockIdx.y * 128;
  const int l  = t & 63, wv = t >> 6;
  const int wr = wv >> 1, wc = wv & 1;
  const int lrow = l & 15, lhi = l >> 4;

  f32x4 acc[4][4] = {};

  for (int kt = 0; kt < Dd; kt += 64) {
#pragma unroll
    for (int p = 0; p < 4; ++p) {
      const int baseRow = p * 32 + wv * 8;
      const int row = baseRow + (l >> 3);
      const int gl  = (l & 7) ^ (row & 7);
      gload16(Ab + (size_t)(m0 + row) * Dd + kt + gl * 8, &As[baseRow * 64]);
      gload16(Bt + (size_t)(n0 + row) * Dd + kt + gl * 8, &Bs[baseRow * 64]);
    }
    __syncthreads();

#pragma unroll
    for (int kk = 0; kk < 2; ++kk) {
      short8t a[4], b[4];
      const int g = kk * 4 + lhi;
#pragma unroll
      for (int i = 0; i < 4; ++i) {
        const int row = wr * 64 + i * 16 + lrow;
        a[i] = *(const short8t*)&As[row * 64 + ((g ^ (row & 7)) << 3)];
      }
#pragma unroll
      for (int j = 0; j < 4; ++j) {
        const int row = wc * 64 + j * 16 + lrow;
        b[j] = *(const short8t*)&Bs[row * 64 + ((g ^ (row & 7)) << 3)];
      }
#pragma unroll
      for (int i = 0; i < 4; ++i)
#pragma unroll
        for (int j = 0; j < 4; ++j)
          acc[i][j] = __builtin_amdgcn_mfma_f32_16x16x32_bf16(a[i], b[j], acc[i][j], 0, 0, 0);
    }
    __syncthreads();
  }

#pragma unroll
  for (int i = 0; i < 4; ++i)
#pragma unroll
    for (int j = 0; j < 4; ++j) {
      const int nn = n0 + wc * 64 + j * 16 + lrow;
#pragma unroll
      for (int r = 0; r < 4; ++r) {
        const int mm = m0 + wr * 64 + i * 16 + lhi * 4 + r;
        Cout[(size_t)mm * Dd + nn] = acc[i][j][r] + bias[nn];
      }
    }
}

// ---------------------------------------------------------------------------
// PV direct (no split-K): 64x128 tile, K=2048, grid (S/64, BH) = 512 blocks.
// A manual f32->bf16 convert; B async; writes bf16 attnb directly (kills the
// pvp f32 partial round-trip + oproj's inline reduce).
// ---------------------------------------------------------------------------
__global__ __launch_bounds__(256) void pv_direct(
    const float* __restrict__ Wts, const ushort* __restrict__ VtAll,
    ushort* __restrict__ attnb)
{
  __shared__ ushort As[64 * 64];    // 8 KB
  __shared__ ushort Bs[128 * 64];   // 16 KB
  const int t  = threadIdx.x;
  const int m0 = blockIdx.x * 64;
  const int z  = blockIdx.y;
  const int l  = t & 63, wv = t >> 6;
  const int wr = wv >> 1, wc = wv & 1;   // wave: 32 rows x 64 dk quadrant
  const int lrow = l & 15, lhi = l >> 4;

  const float*  Af = Wts + (size_t)z * Ss * Ss;
  const ushort* Bt = VtAll + (size_t)z * DKk * Ss;

  f32x4 acc[2][4] = {};

  for (int kt = 0; kt < Ss; kt += 64) {
    // A: 64 rows x 64 k, manual convert (f32 weights -> bf16)
#pragma unroll
    for (int p = 0; p < 2; ++p) {
      const int li = p * 256 + t, row = li >> 3, g = li & 7;
      const int sw = row * 64 + ((g ^ (row & 7)) << 3);
      const float* src = Af + (size_t)(m0 + row) * Ss + kt + g * 8;
      const float4 v0 = *(const float4*)src;
      const float4 v1 = *(const float4*)(src + 4);
      short8t sa;
      sa[0] = (short)f2bf(v0.x); sa[1] = (short)f2bf(v0.y);
      sa[2] = (short)f2bf(v0.z); sa[3] = (short)f2bf(v0.w);
      sa[4] = (short)f2bf(v1.x); sa[5] = (short)f2bf(v1.y);
      sa[6] = (short)f2bf(v1.z); sa[7] = (short)f2bf(v1.w);
      *(short8t*)&As[sw] = sa;
    }
    // B: 128 dk-rows x 64 k, async with source-side swizzle
#pragma unroll
    for (int p = 0; p < 4; ++p) {
      const int baseRow = p * 32 + wv * 8;
      const int brow = baseRow + (l >> 3);
      const int bgl  = (l & 7) ^ (brow & 7);
      gload16(Bt + (size_t)brow * Ss + kt + bgl * 8, &Bs[baseRow * 64]);
    }
    __syncthreads();

#pragma unroll
    for (int kk = 0; kk < 2; ++kk) {
      short8t a[2], b[4];
      const int g = kk * 4 + lhi;
#pragma unroll
      for (int i = 0; i < 2; ++i) {
        const int row = wr * 32 + i * 16 + lrow;
        a[i] = *(const short8t*)&As[row * 64 + ((g ^ (row & 7)) << 3)];
      }
#pragma unroll
      for (int j = 0; j < 4; ++j) {
        const int row = wc * 64 + j * 16 + lrow;
        b[j] = *(const short8t*)&Bs[row * 64 + ((g ^ (row & 7)) << 3)];
      }
#pragma unroll
      for (int i = 0; i < 2; ++i)
#pragma unroll
        for (int j = 0; j < 4; ++j)
          acc[i][j] = __builtin_amdgcn_mfma_f32_16x16x32_bf16(a[i], b[j], acc[i][j], 0, 0, 0);
    }
    __syncthreads();
  }

  const int bb = z >> 3, hh = z & 7;
#pragma unroll
  for (int i = 0; i < 2; ++i)
#pragma unroll
    for (int j = 0; j < 4; ++j) {
      const int nn = wc * 64 + j * 16 + lrow;   // dk in [0,128)
#pragma unroll
      for (int r = 0; r < 4; ++r) {
        const int mm = m0 + wr * 32 + i * 16 + lhi * 4 + r;
        attnb[((size_t)(bb * Ss + mm)) * Dd + hh * DKk + nn] = f2bf(acc[i][j][r]);
      }
    }
}

// ---------------------------------------------------------------------------
// Per-row exact top-512 + softmax, v7: wave-per-row, zero __syncthreads,
// early-exit radix.
// ---------------------------------------------------------------------------
__global__ __launch_bounds__(256) void topk_softmax(float* __restrict__ wts)
{
  __shared__ unsigned histAll[4][1088];

  const int lane = threadIdx.x & 63;
  const int wv   = threadIdx.x >> 6;
  const int row  = blockIdx.x * 4 + wv;
  float* rowp = wts + (size_t)row * Ss;
  unsigned* rowu = (unsigned*)rowp;
  unsigned* h = histAll[wv];

  unsigned k[32];
  unsigned lmax = 0u;
#pragma unroll
  for (int i = 0; i < 8; ++i) {
    const uint4 v = *(const uint4*)(rowu + i * 256 + lane * 4);
    k[i * 4 + 0] = v.x; k[i * 4 + 1] = v.y;
    k[i * 4 + 2] = v.z; k[i * 4 + 3] = v.w;
    lmax = max(max(lmax, max(v.x, v.y)), max(v.z, v.w));
  }
#pragma unroll
  for (int off = 32; off > 0; off >>= 1) lmax = max(lmax, __shfl_xor(lmax, off));
  const float m = key_to_float(lmax);

  unsigned needK = KTOP, tieC = 0u, prefix = 0u;
  unsigned T;

  // pass 1: bits [31:22], 1024 bins
  {
#pragma unroll
    for (int i = 0; i < 17; ++i) h[lane + i * 64] = 0u;
#pragma unroll
    for (int i = 0; i < 32; ++i) {
      const unsigned b = k[i] >> 22;
      atomicAdd(&h[b + (b >> 4)], 1u);
    }
    unsigned b[16], lsum = 0u;
#pragma unroll
    for (int i = 0; i < 16; ++i) { b[i] = h[lane * 17 + i]; lsum += b[i]; }
    unsigned s = lsum;
#pragma unroll
    for (int off = 1; off < 64; off <<= 1) {
      const unsigned v = __shfl_down(s, off);
      if (lane + off < 64) s += v;
    }
    unsigned run = s - lsum;
    unsigned fb = 0u, fn = 0u, ft = 0u;
    bool found = false;
#pragma unroll
    for (int i = 15; i >= 0; --i) {
      const unsigned c = b[i];
      if (!found && c > 0u && run < needK && run + c >= needK) {
        found = true; fb = (unsigned)(lane * 16 + i); fn = needK - run; ft = c;
      }
      run += c;
    }
    const unsigned long long msk = __ballot(found);
    const int src = (int)__ffsll(msk) - 1;
    prefix = __shfl(fb, src) << 22;
    needK  = __shfl(fn, src);
    tieC   = __shfl(ft, src);
  }
  T = prefix;

  if (tieC != needK) {
#pragma unroll
    for (int pass = 0; pass < 2; ++pass) {
      const int sh = (pass == 0) ? 14 : 6;
      const int ph = sh + 8;
#pragma unroll
      for (int i = 0; i < 5; ++i) h[lane + i * 64] = 0u;
      const unsigned pcmp = prefix >> ph;
#pragma unroll
      for (int i = 0; i < 32; ++i) {
        if ((k[i] >> ph) == pcmp) {
          const unsigned b = (k[i] >> sh) & 255u;
          atomicAdd(&h[b + (b >> 4)], 1u);
        }
      }
      unsigned b4[4], lsum = 0u;
#pragma unroll
      for (int i = 0; i < 4; ++i) {
        const unsigned x = (unsigned)(lane * 4 + i);
        b4[i] = h[x + (x >> 4)];
        lsum += b4[i];
      }
      unsigned s = lsum;
#pragma unroll
      for (int off = 1; off < 64; off <<= 1) {
        const unsigned v = __shfl_down(s, off);
        if (lane + off < 64) s += v;
      }
      unsigned run = s - lsum;
      unsigned fb = 0u, fn = 0u, ft = 0u;
      bool found = false;
#pragma unroll
      for (int i = 3; i >= 0; --i) {
        const unsigned c = b4[i];
        if (!found && c > 0u && run < needK && run + c >= needK) {
          found = true; fb = (unsigned)(lane * 4 + i); fn = needK - run; ft = c;
        }
        run += c;
      }
      const unsigned long long msk = __ballot(found);
      const int src = (int)__ffsll(msk) - 1;
      prefix |= __shfl(fb, src) << sh;
      needK   = __shfl(fn, src);
      tieC    = __shfl(ft, src);
      if (tieC == needK) break;
    }
    T = prefix;

    if (tieC != needK) {
      h[lane] = 0u;
      if (lane < 4) h[64 + lane] = 0u;
      const unsigned pcmp = prefix >> 6;
#pragma unroll
      for (int i = 0; i < 32; ++i) {
        if ((k[i] >> 6) == pcmp) {
          const unsigned b = k[i] & 63u;
          atomicAdd(&h[b + (b >> 4)], 1u);
        }
      }
      const unsigned b0 = h[lane + (lane >> 4)];
      unsigned s = b0;
#pragma unroll
      for (int off = 1; off < 64; off <<= 1) {
        const unsigned v = __shfl_down(s, off);
        if (lane + off < 64) s += v;
      }
      const unsigned run = s - b0;
      const bool found = (b0 > 0u && run < needK && run + b0 >= needK);
      const unsigned long long msk = __ballot(found);
      const int src = (int)__ffsll(msk) - 1;
      T     = prefix | (unsigned)__shfl((unsigned)lane, src);
      needK = __shfl(needK - run, src);
      tieC  = __shfl(b0, src);
    }
  }

  if (tieC != needK) {
    unsigned R = 0u;
#pragma unroll
    for (int i = 0; i < 8; ++i) {
      unsigned myEq = 0u;
#pragma unroll
      for (int c = 0; c < 4; ++c) myEq += (k[i * 4 + c] == T);
      unsigned ps = myEq;
#pragma unroll
      for (int off = 1; off < 64; off <<= 1) {
        const unsigned v = __shfl_up(ps, off);
        if (lane >= off) ps += v;
      }
      unsigned before = R + ps - myEq;
#pragma unroll
      for (int c = 0; c < 4; ++c) {
        if (k[i * 4 + c] == T) {
          if (before >= needK) k[i * 4 + c] = 0u;
          ++before;
        }
      }
      R += __shfl(ps, 63);
    }
  }

  float lz = 0.f;
#pragma unroll
  for (int i = 0; i < 32; ++i) {
    const unsigned kk = k[i];
    const float w = (kk >= T) ? __expf(key_to_float(kk) - m) : 0.f;
    k[i] = __float_as_uint(w);
    lz += w;
  }
#pragma unroll
  for (int off = 32; off > 0; off >>= 1) lz += __shfl_xor(lz, off);
  const float Zi = 1.0f / lz;

#pragma unroll
  for (int i = 0; i < 8; ++i) {
    float4 o;
    o.x = __uint_as_float(k[i * 4 + 0]) * Zi;
    o.y = __uint_as_float(k[i * 4 + 1]) * Zi;
    o.z = __uint_as_float(k[i * 4 + 2]) * Zi;
    o.w = __uint_as_float(k[i * 4 + 3]) * Zi;
    *(float4*)(rowu + i * 256 + lane * 4) = o;
  }
}

}  // namespace

extern "C" void kernel_launch(void* const* d_in, const int* in_sizes, int n_in,
                              void* d_out_v, int out_size, void* d_ws, size_t ws_size,
                              hipStream_t stream)
{
  const float* query = (const float*)d_in[0];
  const float* key   = (const float*)d_in[1];
  const float* value = (const float*)d_in[2];
  const float* Wq = (const float*)d_in[3];  const float* bq = (const float*)d_in[4];
  const float* Wk = (const float*)d_in[5];  const float* bk = (const float*)d_in[6];
  const float* Wv = (const float*)d_in[7];  const float* bv = (const float*)d_in[8];
  const float* Wo = (const float*)d_in[9];  const float* bo = (const float*)d_in[10];

  float* d_out = (float*)d_out_v;
  float* outp  = d_out;                              // [B,S,D] f32
  float* wts   = d_out + (size_t)Bb * Ss * Dd;       // [B,H,S,S] f32

  const size_t PROJ = (size_t)MROWS * Dd;            // 4M elements
  const size_t DD2  = (size_t)Dd * Dd;               // 1M elements

  ushort* ws    = (ushort*)d_ws;
  ushort* Qh    = ws;                                // 8 MB each
  ushort* Ql    = Qh + PROJ;
  ushort* Kh    = Ql + PROJ;
  ushort* Kl    = Kh + PROJ;                         // ends at 32 MB
  ushort* wreg  = Kl + PROJ;
  ushort* WqTh  = wreg;                              // 4 x 2 MB splits
  ushort* WqTl  = wreg + DD2;
  ushort* WkTh  = wreg + 2 * DD2;
  ushort* WkTl  = wreg + 3 * DD2;
  ushort* WvT   = wreg + 4 * DD2;                    // 2 MB
  ushort* WoT   = wreg + 5 * DD2;                    // 2 MB
  ushort* Vt    = wreg + 6 * DD2;                    // bf16 V^T [16][128][2048] 8 MB
  ushort* attnb = Qh;                                // aliases Qh (dead after scores)

  // pre-split raw inputs live in the (not-yet-written) wts region of d_out
  ushort* qsh = (ushort*)wts;
  ushort* qsl = qsh + PROJ;
  ushort* ksh = qsh + 2 * PROJ;
  ushort* ksl = qsh + 3 * PROJ;
  ushort* vsb = qsh + 4 * PROJ;

  const dim3 blk(256);

  // weight prep (fused, one launch)
  transpose_prep<<<dim3(32, 32, 4), blk, 0, stream>>>(
      Wq, Wk, Wv, Wo, WqTh, WqTl, WkTh, WkTl, WvT, WoT);

  // pre-split inputs (once, elementwise)
  split_inputs<<<dim3((int)(PROJ / 2048), 3), blk, 0, stream>>>(
      query, key, value, qsh, qsl, ksh, ksl, vsb);

  // Q/K/V projections, batched, 128x128 tile, async staging
  mfma_proj<<<dim3(MROWS / 128, Dd / 128, 3), blk, 0, stream>>>(
      qsh, qsl, ksh, ksl, vsb, WqTh, WqTl, WkTh, WkTl, WvT,
      bq, bk, bv, Qh, Ql, Kh, Kl, Vt);

  // scores -> u32 keys in wts region (SCALE folded)
  mfma_scores<<<dim3(Ss / 128, Ss / 128, BH), blk, 0, stream>>>(
      Qh, Ql, Kh, Kl, (unsigned*)wts);

  // exact top-512 + softmax, in place (wave-per-row, early-exit radix)
  topk_softmax<<<dim3(BH * Ss / 4), blk, 0, stream>>>(wts);

  // PV direct (no split-K) -> bf16 attnb
  pv_direct<<<dim3(Ss / 64, BH), blk, 0, stream>>>(wts, Vt, attnb);

  // output projection (bf16 A, fully async staging)
  mfma_oproj<<<dim3(MROWS / 128, Dd / 128), blk, 0, stream>>>(
      attnb, WoT, bo, outp);
}